// Round 1
// baseline (10461.070 us; speedup 1.0000x reference)
//
#include <hip/hip_runtime.h>
#include <cstdint>

namespace {

constexpr int Lq  = 4096;
constexpr int Bq  = 4;
constexpr int H_  = 16;
constexpr int Mrows = Bq * Lq;               // 16384
constexpr float kScale = 0.17677669529663687f;  // 32^-0.5
constexpr float kEps   = 1e-5f;

// ---------------- big GEMM: C[M,N] = A[M,K] @ W[K,N] ----------------
// EPI: 0 = none, 1 = alpha scale, 2 = silu(x + bias[col])
template<int EPI>
__global__ __launch_bounds__(256)
void gemm_f32(const float* __restrict__ A, const float* __restrict__ W,
              const float* __restrict__ bias, float* __restrict__ C,
              int N, int K, float alpha)
{
  __shared__ float As[16][128];
  __shared__ float Bs[16][128];
  const int tid = threadIdx.x;
  const int bm = blockIdx.y;
  const int bn = blockIdx.x;

  float acc[8][8];
  #pragma unroll
  for (int i = 0; i < 8; ++i) {
    #pragma unroll
    for (int j = 0; j < 8; ++j) acc[i][j] = 0.f;
  }

  const int tm = (tid >> 4) * 8;
  const int tn = (tid & 15) * 8;

  for (int k0 = 0; k0 < K; k0 += 16) {
    #pragma unroll
    for (int i = 0; i < 2; ++i) {
      int s = tid + i * 256;
      int arow = s >> 2, akq = s & 3;
      float4 a4 = *(const float4*)(A + (size_t)(bm * 128 + arow) * K + k0 + akq * 4);
      As[akq * 4 + 0][arow] = a4.x;
      As[akq * 4 + 1][arow] = a4.y;
      As[akq * 4 + 2][arow] = a4.z;
      As[akq * 4 + 3][arow] = a4.w;
      int bkr = s >> 5, bnq = s & 31;
      *(float4*)&Bs[bkr][bnq * 4] =
          *(const float4*)(W + (size_t)(k0 + bkr) * N + bn * 128 + bnq * 4);
    }
    __syncthreads();
    #pragma unroll
    for (int kk = 0; kk < 16; ++kk) {
      float a[8], b[8];
      *(float4*)(a)     = *(const float4*)&As[kk][tm];
      *(float4*)(a + 4) = *(const float4*)&As[kk][tm + 4];
      *(float4*)(b)     = *(const float4*)&Bs[kk][tn];
      *(float4*)(b + 4) = *(const float4*)&Bs[kk][tn + 4];
      #pragma unroll
      for (int i = 0; i < 8; ++i) {
        #pragma unroll
        for (int j = 0; j < 8; ++j)
          acc[i][j] = fmaf(a[i], b[j], acc[i][j]);
      }
    }
    __syncthreads();
  }

  #pragma unroll
  for (int i = 0; i < 8; ++i) {
    size_t row = (size_t)(bm * 128 + tm + i);
    #pragma unroll
    for (int j = 0; j < 8; ++j) {
      float x = acc[i][j];
      if (EPI == 1) x *= alpha;
      if (EPI == 2) {
        int col = bn * 128 + tn + j;
        float z = x + bias[col];
        x = z / (1.f + expf(-z));
      }
      acc[i][j] = x;
    }
    *(float4*)(C + row * N + bn * 128 + tn)     = *(float4*)&acc[i][0];
    *(float4*)(C + row * N + bn * 128 + tn + 4) = *(float4*)&acc[i][4];
  }
}

// ---------------- t1 = x[M,1024] @ Wg1[1024,16] ----------------
__global__ __launch_bounds__(256)
void gemm_g1(const float* __restrict__ x, const float* __restrict__ W1,
             float* __restrict__ t1)
{
  __shared__ float Xs[16][64];
  __shared__ float Ws[64][16];
  const int tid = threadIdx.x;
  const int m0 = blockIdx.x * 16;
  const int mi = tid >> 4, n = tid & 15;
  float acc = 0.f;
  for (int k0 = 0; k0 < 1024; k0 += 64) {
    *(float4*)&Xs[tid >> 4][(tid & 15) * 4] =
        *(const float4*)(x + (size_t)(m0 + (tid >> 4)) * 1024 + k0 + (tid & 15) * 4);
    *(float4*)&Ws[tid >> 2][(tid & 3) * 4] =
        *(const float4*)(W1 + (size_t)(k0 + (tid >> 2)) * 16 + (tid & 3) * 4);
    __syncthreads();
    #pragma unroll
    for (int kk = 0; kk < 64; ++kk)
      acc = fmaf(Xs[mi][kk], Ws[kk][n], acc);
    __syncthreads();
  }
  t1[(size_t)(m0 + mi) * 16 + n] = acc;
}

// --------- g = exp(log_sigmoid(t1 @ Wg2) / 16),  [M, 512] ---------
__global__ __launch_bounds__(256)
void gemm_g2(const float* __restrict__ t1, const float* __restrict__ W2,
             float* __restrict__ g)
{
  const int idx = blockIdx.x * 256 + threadIdx.x;   // < M*512
  const int m = idx >> 9, n = idx & 511;
  float acc = 0.f;
  #pragma unroll
  for (int kk = 0; kk < 16; ++kk)
    acc = fmaf(t1[m * 16 + kk], W2[kk * 512 + n], acc);
  // stable log_sigmoid
  float ls = fminf(acc, 0.f) - log1pf(expf(-fabsf(acc)));
  g[idx] = expf(ls * 0.0625f);
}

// ---------------- sequential GLA scan ----------------
// one 64-lane wave per (b,h); lane e owns state column state[0:32][e]
struct StepRegs {
  float4 q[8], k[8], g[8];
  float v;
};

__device__ __forceinline__ void load_step(StepRegs& s,
    const float4* __restrict__ qb, const float4* __restrict__ kb,
    const float4* __restrict__ gb, const float* __restrict__ vb, int tt)
{
  const size_t ro = (size_t)tt * 128;   // 512 floats per step = 128 float4
  #pragma unroll
  for (int i = 0; i < 8; ++i) {
    s.q[i] = qb[ro + i];
    s.k[i] = kb[ro + i];
    s.g[i] = gb[ro + i];
  }
  s.v = vb[(size_t)tt * 1024];
}

__device__ __forceinline__ float compute_step(const StepRegs& s, float* st)
{
  float o0 = 0.f, o1 = 0.f, o2 = 0.f, o3 = 0.f;
  #pragma unroll
  for (int i = 0; i < 8; ++i) {
    float4 qq = s.q[i], kk = s.k[i], gg = s.g[i];
    st[4*i+0] = fmaf(st[4*i+0], gg.x, kk.x * s.v); o0 = fmaf(qq.x, st[4*i+0], o0);
    st[4*i+1] = fmaf(st[4*i+1], gg.y, kk.y * s.v); o1 = fmaf(qq.y, st[4*i+1], o1);
    st[4*i+2] = fmaf(st[4*i+2], gg.z, kk.z * s.v); o2 = fmaf(qq.z, st[4*i+2], o2);
    st[4*i+3] = fmaf(st[4*i+3], gg.w, kk.w * s.v); o3 = fmaf(qq.w, st[4*i+3], o3);
  }
  return (o0 + o1) + (o2 + o3);
}

__global__ __launch_bounds__(64)
void gla_scan(const float* __restrict__ q, const float* __restrict__ k,
              const float* __restrict__ g, const float* __restrict__ v,
              float* __restrict__ o)
{
  const int bh = blockIdx.x;
  const int b = bh >> 4, h = bh & 15;
  const int e = threadIdx.x;

  const float4* qb = (const float4*)(q + (size_t)b * Lq * 512) + h * 8;
  const float4* kb = (const float4*)(k + (size_t)b * Lq * 512) + h * 8;
  const float4* gb = (const float4*)(g + (size_t)b * Lq * 512) + h * 8;
  const float*  vb = v + (size_t)b * Lq * 1024 + h * 64 + e;
  float*        ob = o + (size_t)b * Lq * 1024 + h * 64 + e;

  float st[32];
  #pragma unroll
  for (int i = 0; i < 32; ++i) st[i] = 0.f;

  StepRegs cur, nxt;
  load_step(cur, qb, kb, gb, vb, 0);
  for (int tt = 0; tt < Lq; tt += 2) {
    load_step(nxt, qb, kb, gb, vb, tt + 1);
    ob[(size_t)tt * 1024] = compute_step(cur, st);
    if (tt + 2 < Lq) load_step(cur, qb, kb, gb, vb, tt + 2);
    ob[(size_t)(tt + 1) * 1024] = compute_step(nxt, st);
  }
}

// --------- group norm over DV=64 + gate multiply (in-place on gate) ---------
__global__ __launch_bounds__(256)
void gnorm_gate(const float* __restrict__ o, float* __restrict__ gate_io)
{
  const int gid = blockIdx.x * 4 + (threadIdx.x >> 6);  // (b*L*H + l*H... ) flat group
  const int e = threadIdx.x & 63;
  const size_t addr = (size_t)gid * 64 + e;
  float val = o[addr];
  float s = val;
  #pragma unroll
  for (int m = 32; m; m >>= 1) s += __shfl_xor(s, m, 64);
  float mean = s * (1.f / 64.f);
  float d = val - mean;
  float s2 = d * d;
  #pragma unroll
  for (int m = 32; m; m >>= 1) s2 += __shfl_xor(s2, m, 64);
  float y = d * rsqrtf(s2 * (1.f / 64.f) + kEps);
  gate_io[addr] = gate_io[addr] * y;
}

} // namespace

extern "C" void kernel_launch(void* const* d_in, const int* in_sizes, int n_in,
                              void* d_out, int out_size, void* d_ws, size_t ws_size,
                              hipStream_t stream)
{
  (void)in_sizes; (void)n_in; (void)out_size; (void)ws_size;
  const float* x   = (const float*)d_in[0];
  const float* Wq  = (const float*)d_in[1];
  const float* Wk  = (const float*)d_in[2];
  const float* Wg1 = (const float*)d_in[3];
  const float* Wg2 = (const float*)d_in[4];
  const float* Wv  = (const float*)d_in[5];
  const float* Wg  = (const float*)d_in[6];
  const float* bg  = (const float*)d_in[7];
  const float* Wo  = (const float*)d_in[8];

  float* ws   = (float*)d_ws;
  float* qb   = ws;                              // M*512
  float* kb   = qb   + (size_t)Mrows * 512;      // M*512
  float* gb   = kb   + (size_t)Mrows * 512;      // M*512
  float* vb   = gb   + (size_t)Mrows * 512;      // M*1024
  float* gate = vb   + (size_t)Mrows * 1024;     // M*1024
  float* t1   = gate + (size_t)Mrows * 1024;     // M*16
  float* oraw = (float*)d_out;                   // scan scratch, overwritten by final GEMM

  const dim3 blk(256);
  // projections
  gemm_f32<0><<<dim3(512 / 128,  Mrows / 128), blk, 0, stream>>>(x, Wq, nullptr, qb, 512, 1024, 0.f);
  gemm_f32<1><<<dim3(512 / 128,  Mrows / 128), blk, 0, stream>>>(x, Wk, nullptr, kb, 512, 1024, kScale);
  gemm_f32<0><<<dim3(1024 / 128, Mrows / 128), blk, 0, stream>>>(x, Wv, nullptr, vb, 1024, 1024, 0.f);
  gemm_f32<2><<<dim3(1024 / 128, Mrows / 128), blk, 0, stream>>>(x, Wg, bg, gate, 1024, 1024, 0.f);
  gemm_g1<<<Mrows / 16, 256, 0, stream>>>(x, Wg1, t1);
  gemm_g2<<<(Mrows * 512) / 256, 256, 0, stream>>>(t1, Wg2, gb);
  // recurrence
  gla_scan<<<Bq * H_, 64, 0, stream>>>(qb, kb, gb, vb, oraw);
  // group-norm + gate (in-place over gate buffer)
  gnorm_gate<<<(Mrows * H_) / 4, 256, 0, stream>>>(oraw, gate);
  // output projection
  gemm_f32<0><<<dim3(1024 / 128, Mrows / 128), blk, 0, stream>>>(gate, Wo, nullptr, (float*)d_out, 1024, 1024, 0.f);
}

// Round 3
// 2057.548 us; speedup vs baseline: 5.0842x; 5.0842x over previous
//
#include <hip/hip_runtime.h>
#include <cstdint>

namespace {

constexpr int Lq  = 4096;
constexpr int Bq  = 4;
constexpr int H_  = 16;
constexpr int Mrows = Bq * Lq;               // 16384
constexpr int CHK  = 64;                     // chunk length
constexpr int NCHK = Lq / CHK;               // 64 chunks
constexpr float kScale = 0.17677669529663687f;  // 32^-0.5
constexpr float kEps   = 1e-5f;

// ---------------- big GEMM: C[M,N] = A[M,K] @ W[K,N] ----------------
// EPI: 0 = none, 1 = alpha scale, 2 = silu(x + bias[col])
template<int EPI>
__global__ __launch_bounds__(256)
void gemm_f32(const float* __restrict__ A, const float* __restrict__ W,
              const float* __restrict__ bias, float* __restrict__ C,
              int N, int K, float alpha)
{
  __shared__ float As[16][128];
  __shared__ float Bs[16][128];
  const int tid = threadIdx.x;
  const int bm = blockIdx.y;
  const int bn = blockIdx.x;

  float acc[8][8];
  #pragma unroll
  for (int i = 0; i < 8; ++i) {
    #pragma unroll
    for (int j = 0; j < 8; ++j) acc[i][j] = 0.f;
  }

  const int tm = (tid >> 4) * 8;
  const int tn = (tid & 15) * 8;

  for (int k0 = 0; k0 < K; k0 += 16) {
    #pragma unroll
    for (int i = 0; i < 2; ++i) {
      int s = tid + i * 256;
      int arow = s >> 2, akq = s & 3;
      float4 a4 = *(const float4*)(A + (size_t)(bm * 128 + arow) * K + k0 + akq * 4);
      As[akq * 4 + 0][arow] = a4.x;
      As[akq * 4 + 1][arow] = a4.y;
      As[akq * 4 + 2][arow] = a4.z;
      As[akq * 4 + 3][arow] = a4.w;
      int bkr = s >> 5, bnq = s & 31;
      *(float4*)&Bs[bkr][bnq * 4] =
          *(const float4*)(W + (size_t)(k0 + bkr) * N + bn * 128 + bnq * 4);
    }
    __syncthreads();
    #pragma unroll
    for (int kk = 0; kk < 16; ++kk) {
      float a[8], b[8];
      *(float4*)(a)     = *(const float4*)&As[kk][tm];
      *(float4*)(a + 4) = *(const float4*)&As[kk][tm + 4];
      *(float4*)(b)     = *(const float4*)&Bs[kk][tn];
      *(float4*)(b + 4) = *(const float4*)&Bs[kk][tn + 4];
      #pragma unroll
      for (int i = 0; i < 8; ++i) {
        #pragma unroll
        for (int j = 0; j < 8; ++j)
          acc[i][j] = fmaf(a[i], b[j], acc[i][j]);
      }
    }
    __syncthreads();
  }

  #pragma unroll
  for (int i = 0; i < 8; ++i) {
    size_t row = (size_t)(bm * 128 + tm + i);
    #pragma unroll
    for (int j = 0; j < 8; ++j) {
      float x = acc[i][j];
      if (EPI == 1) x *= alpha;
      if (EPI == 2) {
        int col = bn * 128 + tn + j;
        float z = x + bias[col];
        x = z / (1.f + expf(-z));
      }
      acc[i][j] = x;
    }
    *(float4*)(C + row * N + bn * 128 + tn)     = *(float4*)&acc[i][0];
    *(float4*)(C + row * N + bn * 128 + tn + 4) = *(float4*)&acc[i][4];
  }
}

// ---------------- t1 = x[M,1024] @ Wg1[1024,16] ----------------
__global__ __launch_bounds__(256)
void gemm_g1(const float* __restrict__ x, const float* __restrict__ W1,
             float* __restrict__ t1)
{
  __shared__ float Xs[16][64];
  __shared__ float Ws[64][16];
  const int tid = threadIdx.x;
  const int m0 = blockIdx.x * 16;
  const int mi = tid >> 4, n = tid & 15;
  float acc = 0.f;
  for (int k0 = 0; k0 < 1024; k0 += 64) {
    *(float4*)&Xs[tid >> 4][(tid & 15) * 4] =
        *(const float4*)(x + (size_t)(m0 + (tid >> 4)) * 1024 + k0 + (tid & 15) * 4);
    *(float4*)&Ws[tid >> 2][(tid & 3) * 4] =
        *(const float4*)(W1 + (size_t)(k0 + (tid >> 2)) * 16 + (tid & 3) * 4);
    __syncthreads();
    #pragma unroll
    for (int kk = 0; kk < 64; ++kk)
      acc = fmaf(Xs[mi][kk], Ws[kk][n], acc);
    __syncthreads();
  }
  t1[(size_t)(m0 + mi) * 16 + n] = acc;
}

// --------- lg = log_sigmoid(t1 @ Wg2) / 16,  [M, 512] (LOG gate) ---------
__global__ __launch_bounds__(256)
void gemm_g2(const float* __restrict__ t1, const float* __restrict__ W2,
             float* __restrict__ lg)
{
  const int idx = blockIdx.x * 256 + threadIdx.x;   // < M*512
  const int m = idx >> 9, n = idx & 511;
  float acc = 0.f;
  #pragma unroll
  for (int kk = 0; kk < 16; ++kk)
    acc = fmaf(t1[m * 16 + kk], W2[kk * 512 + n], acc);
  // stable log_sigmoid, divided by GATE_NORM
  float ls = fminf(acc, 0.f) - log1pf(expf(-fabsf(acc)));
  lg[idx] = ls * 0.0625f;
}

// ============ chunked GLA ============
// Kernel A: per (bh, chunk) -> P[32][64] (local state contribution) and
//           per-dim chunk decay D[32] = exp(sum lg)
__global__ __launch_bounds__(256)
void gla_chunk_state(const float* __restrict__ k, const float* __restrict__ lg,
                     const float* __restrict__ v, float* __restrict__ P,
                     float* __restrict__ Dd)
{
  __shared__ float Lc[CHK][32];   // inclusive cumsum of lg
  __shared__ float kd[CHK][32];   // k * exp(Lsum - Lcum)
  __shared__ float vs[CHK][64];
  const int blk = blockIdx.x;            // bh*NCHK + chunk
  const int bh = blk >> 6, chunk = blk & (NCHK - 1);
  const int b = bh >> 4, h = bh & 15;
  const int tid = threadIdx.x;
  const size_t rowq = ((size_t)b * Lq + (size_t)chunk * CHK) * 512 + h * 32;
  const size_t rowv = ((size_t)b * Lq + (size_t)chunk * CHK) * 1024 + h * 64;

  #pragma unroll
  for (int r = 0; r < 8; ++r) {
    int idx = tid + 256 * r;             // 2048 = 64*32
    int t = idx >> 5, d = idx & 31;
    Lc[t][d] = lg[rowq + (size_t)t * 512 + d];
  }
  __syncthreads();
  if (tid < 32) {
    float s = 0.f;
    for (int t = 0; t < CHK; ++t) { s += Lc[t][tid]; Lc[t][tid] = s; }
  }
  __syncthreads();
  #pragma unroll
  for (int r = 0; r < 8; ++r) {
    int idx = tid + 256 * r;
    int t = idx >> 5, d = idx & 31;
    kd[t][d] = k[rowq + (size_t)t * 512 + d] * expf(Lc[CHK - 1][d] - Lc[t][d]);
  }
  #pragma unroll
  for (int r = 0; r < 16; ++r) {
    int idx = tid + 256 * r;             // 4096
    int t = idx >> 6, e = idx & 63;
    vs[t][e] = v[rowv + (size_t)t * 1024 + e];
  }
  __syncthreads();
  #pragma unroll
  for (int r = 0; r < 8; ++r) {
    int idx = tid + 256 * r;             // 2048 outputs
    int d = idx >> 6, e = idx & 63;
    float a = 0.f;
    #pragma unroll 4
    for (int t = 0; t < CHK; ++t) a = fmaf(kd[t][d], vs[t][e], a);
    P[(size_t)blk * 2048 + idx] = a;
  }
  if (tid < 32) Dd[(size_t)blk * 32 + tid] = expf(Lc[CHK - 1][tid]);
}

// Kernel B: sequential chain over chunks (per bh). In-place: P[i] becomes
// the state at the START of chunk i.
__global__ __launch_bounds__(256)
void gla_chain(float* __restrict__ P, const float* __restrict__ Dd)
{
  const int bh = blockIdx.x;
  const int tid = threadIdx.x;
  float s[8];
  #pragma unroll
  for (int r = 0; r < 8; ++r) s[r] = 0.f;
  for (int i = 0; i < NCHK; ++i) {
    const size_t base = ((size_t)bh * NCHK + i) * 2048;
    const float* dd = Dd + ((size_t)bh * NCHK + i) * 32;
    #pragma unroll
    for (int r = 0; r < 8; ++r) {
      int idx = tid + 256 * r;
      int d = idx >> 6;
      float p = P[base + idx];
      P[base + idx] = s[r];
      s[r] = fmaf(s[r], dd[d], p);
    }
  }
}

// Kernel C: per (bh, chunk) output:
//   o_t = (q_t e^{Lcum_t}) @ S_start + sum_{s<=t} ((q_t e^{Lcum_t}) . (k_s e^{-Lcum_s})) v_s
__global__ __launch_bounds__(256)
void gla_chunk_out(const float* __restrict__ q, const float* __restrict__ k,
                   const float* __restrict__ lg, const float* __restrict__ v,
                   const float* __restrict__ S, float* __restrict__ o)
{
  __shared__ float qs[CHK][33];   // lg -> Lcum -> q*exp(Lcum)   (padded)
  __shared__ float kd[CHK][33];   // k * exp(-Lcum)              (padded)
  __shared__ float vs[CHK][64];
  __shared__ float As[CHK][CHK];
  __shared__ float Ss[32][64];
  const int blk = blockIdx.x;
  const int bh = blk >> 6, chunk = blk & (NCHK - 1);
  const int b = bh >> 4, h = bh & 15;
  const int tid = threadIdx.x;
  const size_t rowq = ((size_t)b * Lq + (size_t)chunk * CHK) * 512 + h * 32;
  const size_t rowv = ((size_t)b * Lq + (size_t)chunk * CHK) * 1024 + h * 64;

  #pragma unroll
  for (int r = 0; r < 8; ++r) {
    int idx = tid + 256 * r;
    int t = idx >> 5, d = idx & 31;
    qs[t][d] = lg[rowq + (size_t)t * 512 + d];
  }
  __syncthreads();
  if (tid < 32) {
    float s = 0.f;
    for (int t = 0; t < CHK; ++t) { s += qs[t][tid]; qs[t][tid] = s; }
  }
  __syncthreads();
  // k'' = k * exp(-Lcum)  (reads qs = Lcum)
  #pragma unroll
  for (int r = 0; r < 8; ++r) {
    int idx = tid + 256 * r;
    int t = idx >> 5, d = idx & 31;
    kd[t][d] = k[rowq + (size_t)t * 512 + d] * expf(-qs[t][d]);
  }
  __syncthreads();   // all Lcum reads done before overwrite
  // q' = q * exp(Lcum), in place (element-wise)
  #pragma unroll
  for (int r = 0; r < 8; ++r) {
    int idx = tid + 256 * r;
    int t = idx >> 5, d = idx & 31;
    qs[t][d] = q[rowq + (size_t)t * 512 + d] * expf(qs[t][d]);
  }
  #pragma unroll
  for (int r = 0; r < 16; ++r) {
    int idx = tid + 256 * r;
    int t = idx >> 6, e = idx & 63;
    vs[t][e] = v[rowv + (size_t)t * 1024 + e];
  }
  #pragma unroll
  for (int r = 0; r < 8; ++r) {
    int idx = tid + 256 * r;             // 2048 = 32*64
    Ss[idx >> 6][idx & 63] = S[(size_t)blk * 2048 + idx];
  }
  __syncthreads();
  // A[t][s] = (s<=t) ? q'_t . k''_s : 0
  #pragma unroll
  for (int r = 0; r < 16; ++r) {
    int idx = tid + 256 * r;             // 4096
    int t = idx >> 6, s = idx & 63;
    float a = 0.f;
    if (s <= t) {
      #pragma unroll 8
      for (int d = 0; d < 32; ++d) a = fmaf(qs[t][d], kd[s][d], a);
    }
    As[t][s] = a;
  }
  __syncthreads();
  // o[t][e] = A[t][:] . v[:][e] + q'_t . S[:,e]
  #pragma unroll
  for (int r = 0; r < 16; ++r) {
    int idx = tid + 256 * r;
    int t = idx >> 6, e = idx & 63;
    float a = 0.f;
    #pragma unroll 4
    for (int s = 0; s <= t; ++s) a = fmaf(As[t][s], vs[s][e], a);
    #pragma unroll 8
    for (int d = 0; d < 32; ++d) a = fmaf(qs[t][d], Ss[d][e], a);
    o[((size_t)b * Lq + (size_t)chunk * CHK + t) * 1024 + h * 64 + e] = a;
  }
}

// --------- group norm over DV=64 + gate multiply (in-place on gate) ---------
__global__ __launch_bounds__(256)
void gnorm_gate(const float* __restrict__ o, float* __restrict__ gate_io)
{
  const int gid = blockIdx.x * 4 + (threadIdx.x >> 6);
  const int e = threadIdx.x & 63;
  const size_t addr = (size_t)gid * 64 + e;
  float val = o[addr];
  float s = val;
  #pragma unroll
  for (int m = 32; m; m >>= 1) s += __shfl_xor(s, m, 64);
  float mean = s * (1.f / 64.f);
  float d = val - mean;
  float s2 = d * d;
  #pragma unroll
  for (int m = 32; m; m >>= 1) s2 += __shfl_xor(s2, m, 64);
  float y = d * rsqrtf(s2 * (1.f / 64.f) + kEps);
  gate_io[addr] = gate_io[addr] * y;
}

} // namespace

extern "C" void kernel_launch(void* const* d_in, const int* in_sizes, int n_in,
                              void* d_out, int out_size, void* d_ws, size_t ws_size,
                              hipStream_t stream)
{
  (void)in_sizes; (void)n_in; (void)out_size; (void)ws_size;
  const float* x   = (const float*)d_in[0];
  const float* Wq  = (const float*)d_in[1];
  const float* Wk  = (const float*)d_in[2];
  const float* Wg1 = (const float*)d_in[3];
  const float* Wg2 = (const float*)d_in[4];
  const float* Wv  = (const float*)d_in[5];
  const float* Wg  = (const float*)d_in[6];
  const float* bg  = (const float*)d_in[7];
  const float* Wo  = (const float*)d_in[8];

  // Workspace layout (floats). Total = 50.73 M floats = 202.9 MB.
  // gate (M*1024) ALIASES kb+lgb after the recurrence consumes them.
  float* ws   = (float*)d_ws;
  float* qb   = ws;                              // M*512
  float* kb   = qb   + (size_t)Mrows * 512;      // M*512
  float* lgb  = kb   + (size_t)Mrows * 512;      // M*512 (log gate)
  float* vb   = lgb  + (size_t)Mrows * 512;      // M*1024
  float* t1   = vb   + (size_t)Mrows * 1024;     // M*16
  float* Pst  = t1   + (size_t)Mrows * 16;       // 64*64*2048 (P -> chunk-start states)
  float* Dd   = Pst  + (size_t)64 * NCHK * 2048; // 64*64*32
  float* gate = kb;                              // alias: reuses kb+lgb (M*1024) post-scan
  float* oraw = (float*)d_out;                   // scan output scratch

  const dim3 blk(256);
  // projections (NO gate GEMM yet -- its buffer aliases kb/lgb)
  gemm_f32<0><<<dim3(512 / 128,  Mrows / 128), blk, 0, stream>>>(x, Wq, nullptr, qb, 512, 1024, 0.f);
  gemm_f32<1><<<dim3(512 / 128,  Mrows / 128), blk, 0, stream>>>(x, Wk, nullptr, kb, 512, 1024, kScale);
  gemm_f32<0><<<dim3(1024 / 128, Mrows / 128), blk, 0, stream>>>(x, Wv, nullptr, vb, 1024, 1024, 0.f);
  gemm_g1<<<Mrows / 16, 256, 0, stream>>>(x, Wg1, t1);
  gemm_g2<<<(Mrows * 512) / 256, 256, 0, stream>>>(t1, Wg2, lgb);
  // chunked recurrence
  gla_chunk_state<<<64 * NCHK, blk, 0, stream>>>(kb, lgb, vb, Pst, Dd);
  gla_chain<<<64, blk, 0, stream>>>(Pst, Dd);
  gla_chunk_out<<<64 * NCHK, blk, 0, stream>>>(qb, kb, lgb, vb, Pst, oraw);
  // NOW k/lg are dead: compute SiLU gate into their storage
  gemm_f32<2><<<dim3(1024 / 128, Mrows / 128), blk, 0, stream>>>(x, Wg, bg, gate, 1024, 1024, 0.f);
  // group-norm + gate (in-place over gate buffer)
  gnorm_gate<<<(Mrows * H_) / 4, 256, 0, stream>>>(oraw, gate);
  // output projection (overwrites oraw scratch in d_out)
  gemm_f32<0><<<dim3(1024 / 128, Mrows / 128), blk, 0, stream>>>(gate, Wo, nullptr, (float*)d_out, 1024, 1024, 0.f);
}

// Round 4
// 709.837 us; speedup vs baseline: 14.7373x; 2.8986x over previous
//
#include <hip/hip_runtime.h>
#include <cstdint>

namespace {

constexpr int Lq  = 4096;
constexpr int Bq  = 4;
constexpr int H_  = 16;
constexpr int Mrows = Bq * Lq;               // 16384
constexpr int CHK  = 64;
constexpr int NCHK = Lq / CHK;               // 64
constexpr float kScale = 0.17677669529663687f;  // 32^-0.5
constexpr float kEps   = 1e-5f;

typedef __attribute__((ext_vector_type(8))) short short8;
typedef __attribute__((ext_vector_type(4))) float f32x4;

__device__ __forceinline__ float bf2f(unsigned short u) {
  return __uint_as_float(((unsigned)u) << 16);
}
__device__ __forceinline__ unsigned short f2bf(float f) {
  unsigned u = __float_as_uint(f);
  u += 0x7fffu + ((u >> 16) & 1u);   // RNE
  return (unsigned short)(u >> 16);
}
__device__ __forceinline__ void gload_lds16(const void* g, void* l) {
  __builtin_amdgcn_global_load_lds(
      (const __attribute__((address_space(1))) void*)g,
      (__attribute__((address_space(3))) void*)l, 16, 0, 0);
}

// ---------- x fp32 -> bf16 ----------
__global__ __launch_bounds__(256)
void cvt_bf16(const float* __restrict__ in, unsigned short* __restrict__ out, int n4)
{
  int i = blockIdx.x * 256 + threadIdx.x;
  const int stride = gridDim.x * 256;
  for (; i < n4; i += stride) {
    float4 f = ((const float4*)in)[i];
    ushort4 u = make_ushort4(f2bf(f.x), f2bf(f.y), f2bf(f.z), f2bf(f.w));
    ((ushort4*)out)[i] = u;
  }
}

// ---------- W[K,N] fp32 -> Wt[N,K] bf16 (optionally scaled) ----------
__global__ __launch_bounds__(256)
void cvt_w_t(const float* __restrict__ W, unsigned short* __restrict__ Wt,
             int K, int N, float scale)
{
  __shared__ float T[64][65];
  const int tid = threadIdx.x;
  const int n0 = blockIdx.x * 64, k0 = blockIdx.y * 64;
  #pragma unroll
  for (int it = 0; it < 4; ++it) {
    int kr = (tid >> 4) + it * 16;
    float4 f = *(const float4*)(W + (size_t)(k0 + kr) * N + n0 + (tid & 15) * 4);
    T[kr][(tid & 15) * 4 + 0] = f.x;
    T[kr][(tid & 15) * 4 + 1] = f.y;
    T[kr][(tid & 15) * 4 + 2] = f.z;
    T[kr][(tid & 15) * 4 + 3] = f.w;
  }
  __syncthreads();
  #pragma unroll
  for (int it = 0; it < 4; ++it) {
    int nr = (tid >> 4) + it * 16;
    int c0 = (tid & 15) * 4;
    ushort4 u = make_ushort4(f2bf(T[c0 + 0][nr] * scale), f2bf(T[c0 + 1][nr] * scale),
                             f2bf(T[c0 + 2][nr] * scale), f2bf(T[c0 + 3][nr] * scale));
    *(ushort4*)(Wt + (size_t)(n0 + nr) * K + k0 + c0) = u;
  }
}

// ---------- bf16 MFMA GEMM: C[M,N] = A[M,1024] @ Wt[N,1024]^T ----------
// EPI: 0 = store bf16; 2 = silu(x+bias[col]) store bf16; 3 = store fp32
template<int EPI>
__global__ __launch_bounds__(256)
void gemm_bf16(const unsigned short* __restrict__ A,
               const unsigned short* __restrict__ Bt,
               const float* __restrict__ bias,
               void* __restrict__ Cout, int N)
{
  __shared__ unsigned short As[2][128 * 32];
  __shared__ unsigned short Bs[2][128 * 32];
  const int tid = threadIdx.x;
  const int w = tid >> 6, l = tid & 63;
  const int wr = w >> 1, wc = w & 1;
  const int m0 = blockIdx.y * 128, n0 = blockIdx.x * 128;

  // staging: physical LDS slot -> logical (row,k) via involution p^(((p>>7)&3)<<4)
  const unsigned short* gA[2];
  const unsigned short* gB[2];
  #pragma unroll
  for (int i = 0; i < 2; ++i) {
    int p = (i * 256 + tid) * 16;
    int L = p ^ (((p >> 7) & 3) << 4);
    int r = L >> 6;
    int ke = (L & 63) >> 1;
    gA[i] = A  + (size_t)(m0 + r) * 1024 + ke;
    gB[i] = Bt + (size_t)(n0 + r) * 1024 + ke;
  }
  // fragment read offsets (swizzled, loop-invariant)
  int pA[4], pB[4];
  #pragma unroll
  for (int f = 0; f < 4; ++f) {
    int rA = wr * 64 + f * 16 + (l & 15);
    int LA = rA * 64 + (l >> 4) * 16;
    pA[f] = LA ^ (((LA >> 7) & 3) << 4);
    int rB = wc * 64 + f * 16 + (l & 15);
    int LB = rB * 64 + (l >> 4) * 16;
    pB[f] = LB ^ (((LB >> 7) & 3) << 4);
  }

  f32x4 acc[4][4];
  #pragma unroll
  for (int i = 0; i < 4; ++i)
    #pragma unroll
    for (int j = 0; j < 4; ++j)
      acc[i][j] = (f32x4){0.f, 0.f, 0.f, 0.f};

  #pragma unroll
  for (int i = 0; i < 2; ++i) {
    gload_lds16(gA[i], &As[0][(i * 256 + w * 64) * 8]);
    gload_lds16(gB[i], &Bs[0][(i * 256 + w * 64) * 8]);
  }
  __syncthreads();

  int buf = 0;
  for (int ks = 0; ks < 32; ++ks) {
    if (ks < 31) {
      const int k0 = (ks + 1) * 32;
      #pragma unroll
      for (int i = 0; i < 2; ++i) {
        gload_lds16(gA[i] + k0, &As[buf ^ 1][(i * 256 + w * 64) * 8]);
        gload_lds16(gB[i] + k0, &Bs[buf ^ 1][(i * 256 + w * 64) * 8]);
      }
    }
    short8 av[4], bv[4];
    #pragma unroll
    for (int f = 0; f < 4; ++f) {
      av[f] = *(const short8*)((const char*)&As[buf][0] + pA[f]);
      bv[f] = *(const short8*)((const char*)&Bs[buf][0] + pB[f]);
    }
    #pragma unroll
    for (int fi = 0; fi < 4; ++fi)
      #pragma unroll
      for (int fj = 0; fj < 4; ++fj)
        acc[fi][fj] = __builtin_amdgcn_mfma_f32_16x16x32_bf16(
            av[fi], bv[fj], acc[fi][fj], 0, 0, 0);
    __syncthreads();
    buf ^= 1;
  }

  const int cr = (l >> 4) * 4;
  const int cc = l & 15;
  #pragma unroll
  for (int fi = 0; fi < 4; ++fi) {
    #pragma unroll
    for (int fj = 0; fj < 4; ++fj) {
      int row = m0 + wr * 64 + fi * 16 + cr;
      int col = n0 + wc * 64 + fj * 16 + cc;
      float bcol = (EPI == 2) ? bias[col] : 0.f;
      #pragma unroll
      for (int j = 0; j < 4; ++j) {
        float x = acc[fi][fj][j];
        if (EPI == 2) {
          float z = x + bcol;
          x = z / (1.f + expf(-z));
        }
        if (EPI == 3)
          ((float*)Cout)[(size_t)(row + j) * N + col] = x;
        else
          ((unsigned short*)Cout)[(size_t)(row + j) * N + col] = f2bf(x);
      }
    }
  }
}

// ---------------- t1 = x[M,1024] @ Wg1[1024,16] (fp32) ----------------
__global__ __launch_bounds__(256)
void gemm_g1(const float* __restrict__ x, const float* __restrict__ W1,
             float* __restrict__ t1)
{
  __shared__ float Xs[16][64];
  __shared__ float Ws[64][16];
  const int tid = threadIdx.x;
  const int m0 = blockIdx.x * 16;
  const int mi = tid >> 4, n = tid & 15;
  float acc = 0.f;
  for (int k0 = 0; k0 < 1024; k0 += 64) {
    *(float4*)&Xs[tid >> 4][(tid & 15) * 4] =
        *(const float4*)(x + (size_t)(m0 + (tid >> 4)) * 1024 + k0 + (tid & 15) * 4);
    *(float4*)&Ws[tid >> 2][(tid & 3) * 4] =
        *(const float4*)(W1 + (size_t)(k0 + (tid >> 2)) * 16 + (tid & 3) * 4);
    __syncthreads();
    #pragma unroll
    for (int kk = 0; kk < 64; ++kk)
      acc = fmaf(Xs[mi][kk], Ws[kk][n], acc);
    __syncthreads();
  }
  t1[(size_t)(m0 + mi) * 16 + n] = acc;
}

// --------- lg = log_sigmoid(t1 @ Wg2) / 16,  [M, 512] fp32 ---------
__global__ __launch_bounds__(256)
void gemm_g2(const float* __restrict__ t1, const float* __restrict__ W2,
             float* __restrict__ lg)
{
  const int idx = blockIdx.x * 256 + threadIdx.x;
  const int m = idx >> 9, n = idx & 511;
  float acc = 0.f;
  #pragma unroll
  for (int kk = 0; kk < 16; ++kk)
    acc = fmaf(t1[m * 16 + kk], W2[kk * 512 + n], acc);
  float ls = fminf(acc, 0.f) - log1pf(expf(-fabsf(acc)));
  lg[idx] = ls * 0.0625f;
}

// ============ chunked GLA (bf16 q/k/v inputs, fp32 math) ============
__global__ __launch_bounds__(256)
void gla_chunk_state(const unsigned short* __restrict__ k, const float* __restrict__ lg,
                     const unsigned short* __restrict__ v, float* __restrict__ P,
                     float* __restrict__ Dd)
{
  __shared__ float Lc[CHK][32];
  __shared__ float kd[CHK][32];
  __shared__ float vs[CHK][64];
  const int blk = blockIdx.x;
  const int bh = blk >> 6, chunk = blk & (NCHK - 1);
  const int b = bh >> 4, h = bh & 15;
  const int tid = threadIdx.x;
  const size_t rowq = ((size_t)b * Lq + (size_t)chunk * CHK) * 512 + h * 32;
  const size_t rowv = ((size_t)b * Lq + (size_t)chunk * CHK) * 1024 + h * 64;

  #pragma unroll
  for (int r = 0; r < 2; ++r) {
    int s4 = (tid + 256 * r) * 4;
    int t = s4 >> 5, d0 = s4 & 31;
    *(float4*)&Lc[t][d0] = *(const float4*)(lg + rowq + (size_t)t * 512 + d0);
  }
  __syncthreads();
  if (tid < 32) {
    float s = 0.f;
    for (int t = 0; t < CHK; ++t) { s += Lc[t][tid]; Lc[t][tid] = s; }
  }
  __syncthreads();
  #pragma unroll
  for (int r = 0; r < 2; ++r) {
    int s4 = (tid + 256 * r) * 4;
    int t = s4 >> 5, d0 = s4 & 31;
    ushort4 kv = *(const ushort4*)(k + rowq + (size_t)t * 512 + d0);
    kd[t][d0 + 0] = bf2f(kv.x) * expf(Lc[CHK - 1][d0 + 0] - Lc[t][d0 + 0]);
    kd[t][d0 + 1] = bf2f(kv.y) * expf(Lc[CHK - 1][d0 + 1] - Lc[t][d0 + 1]);
    kd[t][d0 + 2] = bf2f(kv.z) * expf(Lc[CHK - 1][d0 + 2] - Lc[t][d0 + 2]);
    kd[t][d0 + 3] = bf2f(kv.w) * expf(Lc[CHK - 1][d0 + 3] - Lc[t][d0 + 3]);
  }
  #pragma unroll
  for (int r = 0; r < 4; ++r) {
    int s4 = (tid + 256 * r) * 4;
    int t = s4 >> 6, e0 = s4 & 63;
    ushort4 vv = *(const ushort4*)(v + rowv + (size_t)t * 1024 + e0);
    vs[t][e0 + 0] = bf2f(vv.x);
    vs[t][e0 + 1] = bf2f(vv.y);
    vs[t][e0 + 2] = bf2f(vv.z);
    vs[t][e0 + 3] = bf2f(vv.w);
  }
  __syncthreads();
  #pragma unroll
  for (int r = 0; r < 8; ++r) {
    int idx = tid + 256 * r;
    int d = idx >> 6, e = idx & 63;
    float a = 0.f;
    #pragma unroll 4
    for (int t = 0; t < CHK; ++t) a = fmaf(kd[t][d], vs[t][e], a);
    P[(size_t)blk * 2048 + idx] = a;
  }
  if (tid < 32) Dd[(size_t)blk * 32 + tid] = expf(Lc[CHK - 1][tid]);
}

__global__ __launch_bounds__(256)
void gla_chain(float* __restrict__ P, const float* __restrict__ Dd)
{
  const int bh = blockIdx.x;
  const int tid = threadIdx.x;
  float4 sA = {0.f, 0.f, 0.f, 0.f}, sB = {0.f, 0.f, 0.f, 0.f};
  const int fA = tid * 4, fB = tid * 4 + 1024;
  const int dA = fA >> 6, dB = fB >> 6;
  for (int i = 0; i < NCHK; ++i) {
    const size_t base = ((size_t)bh * NCHK + i) * 2048;
    const float* dd = Dd + ((size_t)bh * NCHK + i) * 32;
    float4 pa = *(const float4*)(P + base + fA);
    float4 pb = *(const float4*)(P + base + fB);
    *(float4*)(P + base + fA) = sA;
    *(float4*)(P + base + fB) = sB;
    float ga = dd[dA], gb = dd[dB];
    sA.x = fmaf(sA.x, ga, pa.x); sA.y = fmaf(sA.y, ga, pa.y);
    sA.z = fmaf(sA.z, ga, pa.z); sA.w = fmaf(sA.w, ga, pa.w);
    sB.x = fmaf(sB.x, gb, pb.x); sB.y = fmaf(sB.y, gb, pb.y);
    sB.z = fmaf(sB.z, gb, pb.z); sB.w = fmaf(sB.w, gb, pb.w);
  }
}

__global__ __launch_bounds__(256)
void gla_chunk_out(const unsigned short* __restrict__ q, const unsigned short* __restrict__ k,
                   const float* __restrict__ lg, const unsigned short* __restrict__ v,
                   const float* __restrict__ S, float* __restrict__ o)
{
  __shared__ float qs[CHK][33];
  __shared__ float kd[CHK][33];
  __shared__ float vs[CHK][64];
  __shared__ float As[CHK][CHK];
  __shared__ float Ss[32][64];
  const int blk = blockIdx.x;
  const int bh = blk >> 6, chunk = blk & (NCHK - 1);
  const int b = bh >> 4, h = bh & 15;
  const int tid = threadIdx.x;
  const size_t rowq = ((size_t)b * Lq + (size_t)chunk * CHK) * 512 + h * 32;
  const size_t rowv = ((size_t)b * Lq + (size_t)chunk * CHK) * 1024 + h * 64;

  #pragma unroll
  for (int r = 0; r < 2; ++r) {
    int s4 = (tid + 256 * r) * 4;
    int t = s4 >> 5, d0 = s4 & 31;
    float4 f = *(const float4*)(lg + rowq + (size_t)t * 512 + d0);
    qs[t][d0 + 0] = f.x; qs[t][d0 + 1] = f.y;
    qs[t][d0 + 2] = f.z; qs[t][d0 + 3] = f.w;
  }
  __syncthreads();
  if (tid < 32) {
    float s = 0.f;
    for (int t = 0; t < CHK; ++t) { s += qs[t][tid]; qs[t][tid] = s; }
  }
  __syncthreads();
  #pragma unroll
  for (int r = 0; r < 2; ++r) {
    int s4 = (tid + 256 * r) * 4;
    int t = s4 >> 5, d0 = s4 & 31;
    ushort4 kv = *(const ushort4*)(k + rowq + (size_t)t * 512 + d0);
    kd[t][d0 + 0] = bf2f(kv.x) * expf(-qs[t][d0 + 0]);
    kd[t][d0 + 1] = bf2f(kv.y) * expf(-qs[t][d0 + 1]);
    kd[t][d0 + 2] = bf2f(kv.z) * expf(-qs[t][d0 + 2]);
    kd[t][d0 + 3] = bf2f(kv.w) * expf(-qs[t][d0 + 3]);
  }
  __syncthreads();
  #pragma unroll
  for (int r = 0; r < 2; ++r) {
    int s4 = (tid + 256 * r) * 4;
    int t = s4 >> 5, d0 = s4 & 31;
    ushort4 qv = *(const ushort4*)(q + rowq + (size_t)t * 512 + d0);
    qs[t][d0 + 0] = bf2f(qv.x) * expf(qs[t][d0 + 0]);
    qs[t][d0 + 1] = bf2f(qv.y) * expf(qs[t][d0 + 1]);
    qs[t][d0 + 2] = bf2f(qv.z) * expf(qs[t][d0 + 2]);
    qs[t][d0 + 3] = bf2f(qv.w) * expf(qs[t][d0 + 3]);
  }
  #pragma unroll
  for (int r = 0; r < 4; ++r) {
    int s4 = (tid + 256 * r) * 4;
    int t = s4 >> 6, e0 = s4 & 63;
    ushort4 vv = *(const ushort4*)(v + rowv + (size_t)t * 1024 + e0);
    vs[t][e0 + 0] = bf2f(vv.x);
    vs[t][e0 + 1] = bf2f(vv.y);
    vs[t][e0 + 2] = bf2f(vv.z);
    vs[t][e0 + 3] = bf2f(vv.w);
  }
  #pragma unroll
  for (int r = 0; r < 2; ++r) {
    int s4 = (tid + 256 * r) * 4;
    *(float4*)&((float*)Ss)[s4] = *(const float4*)(S + (size_t)blk * 2048 + s4);
  }
  __syncthreads();
  #pragma unroll
  for (int r = 0; r < 16; ++r) {
    int idx = tid + 256 * r;
    int t = idx >> 6, s = idx & 63;
    float a = 0.f;
    if (s <= t) {
      #pragma unroll 8
      for (int d = 0; d < 32; ++d) a = fmaf(qs[t][d], kd[s][d], a);
    }
    As[t][s] = a;
  }
  __syncthreads();
  #pragma unroll
  for (int r = 0; r < 16; ++r) {
    int idx = tid + 256 * r;
    int t = idx >> 6, e = idx & 63;
    float a = 0.f;
    #pragma unroll 4
    for (int s = 0; s <= t; ++s) a = fmaf(As[t][s], vs[s][e], a);
    #pragma unroll 8
    for (int d = 0; d < 32; ++d) a = fmaf(qs[t][d], Ss[d][e], a);
    o[((size_t)b * Lq + (size_t)chunk * CHK + t) * 1024 + h * 64 + e] = a;
  }
}

// --------- group norm + gate multiply -> bf16 A-operand ---------
__global__ __launch_bounds__(256)
void gnorm_gate(const float* __restrict__ o, const unsigned short* __restrict__ gate,
                unsigned short* __restrict__ gated)
{
  const int gid = blockIdx.x * 4 + (threadIdx.x >> 6);
  const int e = threadIdx.x & 63;
  const size_t addr = (size_t)gid * 64 + e;
  float val = o[addr];
  float s = val;
  #pragma unroll
  for (int m = 32; m; m >>= 1) s += __shfl_xor(s, m, 64);
  float mean = s * (1.f / 64.f);
  float d = val - mean;
  float s2 = d * d;
  #pragma unroll
  for (int m = 32; m; m >>= 1) s2 += __shfl_xor(s2, m, 64);
  float y = d * rsqrtf(s2 * (1.f / 64.f) + kEps);
  gated[addr] = f2bf(bf2f(gate[addr]) * y);
}

} // namespace

extern "C" void kernel_launch(void* const* d_in, const int* in_sizes, int n_in,
                              void* d_out, int out_size, void* d_ws, size_t ws_size,
                              hipStream_t stream)
{
  (void)in_sizes; (void)n_in; (void)out_size; (void)ws_size;
  const float* x   = (const float*)d_in[0];
  const float* Wq  = (const float*)d_in[1];
  const float* Wk  = (const float*)d_in[2];
  const float* Wg1 = (const float*)d_in[3];
  const float* Wg2 = (const float*)d_in[4];
  const float* Wv  = (const float*)d_in[5];
  const float* Wg  = (const float*)d_in[6];
  const float* bg  = (const float*)d_in[7];
  const float* Wo  = (const float*)d_in[8];

  // workspace: 177.7 MB total
  char* w = (char*)d_ws;
  unsigned short* xh  = (unsigned short*)w; w += (size_t)Mrows * 1024 * 2;
  unsigned short* qh  = (unsigned short*)w; w += (size_t)Mrows * 512 * 2;
  unsigned short* kh  = (unsigned short*)w; w += (size_t)Mrows * 512 * 2;
  unsigned short* vh  = (unsigned short*)w; w += (size_t)Mrows * 1024 * 2;
  float*  lgb = (float*)w;                  w += (size_t)Mrows * 512 * 4;
  float*  t1  = (float*)w;                  w += (size_t)Mrows * 16 * 4;
  float*  Pst = (float*)w;                  w += (size_t)64 * NCHK * 2048 * 4;
  float*  Dd  = (float*)w;                  w += (size_t)64 * NCHK * 32 * 4;
  unsigned short* Wqt = (unsigned short*)w; w += (size_t)512 * 1024 * 2;
  unsigned short* Wkt = (unsigned short*)w; w += (size_t)512 * 1024 * 2;
  unsigned short* Wvt = (unsigned short*)w; w += (size_t)1024 * 1024 * 2;
  unsigned short* Wgt = (unsigned short*)w; w += (size_t)1024 * 1024 * 2;
  unsigned short* Wot = (unsigned short*)w; w += (size_t)1024 * 1024 * 2;
  // aliases (dead-after-recurrence regions)
  unsigned short* gateh  = qh;            // M*1024 bf16 over qh+kh
  unsigned short* gatedh = (unsigned short*)lgb;  // M*1024 bf16 over lgb

  // dtype conversions
  cvt_bf16<<<2048, 256, 0, stream>>>(x, xh, Mrows * 1024 / 4);
  cvt_w_t<<<dim3(8, 16),  256, 0, stream>>>(Wq, Wqt, 1024, 512, 1.f);
  cvt_w_t<<<dim3(8, 16),  256, 0, stream>>>(Wk, Wkt, 1024, 512, kScale);
  cvt_w_t<<<dim3(16, 16), 256, 0, stream>>>(Wv, Wvt, 1024, 1024, 1.f);
  cvt_w_t<<<dim3(16, 16), 256, 0, stream>>>(Wg, Wgt, 1024, 1024, 1.f);
  cvt_w_t<<<dim3(16, 16), 256, 0, stream>>>(Wo, Wot, 1024, 1024, 1.f);
  // projections (MFMA)
  gemm_bf16<0><<<dim3(4, 128), 256, 0, stream>>>(xh, Wqt, nullptr, qh, 512);
  gemm_bf16<0><<<dim3(4, 128), 256, 0, stream>>>(xh, Wkt, nullptr, kh, 512);
  gemm_bf16<0><<<dim3(8, 128), 256, 0, stream>>>(xh, Wvt, nullptr, vh, 1024);
  gemm_g1<<<Mrows / 16, 256, 0, stream>>>(x, Wg1, t1);
  gemm_g2<<<(Mrows * 512) / 256, 256, 0, stream>>>(t1, Wg2, lgb);
  // chunked recurrence
  gla_chunk_state<<<64 * NCHK, 256, 0, stream>>>(kh, lgb, vh, Pst, Dd);
  gla_chain<<<64, 256, 0, stream>>>(Pst, Dd);
  gla_chunk_out<<<64 * NCHK, 256, 0, stream>>>(qh, kh, lgb, vh, Pst, (float*)d_out);
  // gate path (qh/kh now dead -> gateh alias)
  gemm_bf16<2><<<dim3(8, 128), 256, 0, stream>>>(xh, Wgt, bg, gateh, 1024);
  gnorm_gate<<<(Mrows * H_) / 4, 256, 0, stream>>>((const float*)d_out, gateh, gatedh);
  // output projection
  gemm_bf16<3><<<dim3(8, 128), 256, 0, stream>>>(gatedh, Wot, nullptr, d_out, 1024);
}

// Round 5
// 482.670 us; speedup vs baseline: 21.6734x; 1.4706x over previous
//
#include <hip/hip_runtime.h>
#include <cstdint>

namespace {

constexpr int Lq  = 4096;
constexpr int Bq  = 4;
constexpr int H_  = 16;
constexpr int Mrows = Bq * Lq;               // 16384
constexpr int CHK  = 64;
constexpr int NCHK = Lq / CHK;               // 64
constexpr float kScale = 0.17677669529663687f;  // 32^-0.5
constexpr float kEps   = 1e-5f;

typedef __attribute__((ext_vector_type(8))) short short8;
typedef __attribute__((ext_vector_type(4))) float f32x4;

__device__ __forceinline__ float bf2f(unsigned short u) {
  return __uint_as_float(((unsigned)u) << 16);
}
__device__ __forceinline__ unsigned short f2bf(float f) {
  unsigned u = __float_as_uint(f);
  u += 0x7fffu + ((u >> 16) & 1u);   // RNE
  return (unsigned short)(u >> 16);
}
__device__ __forceinline__ void gload_lds16(const void* g, void* l) {
  __builtin_amdgcn_global_load_lds(
      (const __attribute__((address_space(1))) void*)g,
      (__attribute__((address_space(3))) void*)l, 16, 0, 0);
}

// ---------- x fp32 -> bf16 ----------
__global__ __launch_bounds__(256)
void cvt_bf16(const float* __restrict__ in, unsigned short* __restrict__ out, int n4)
{
  int i = blockIdx.x * 256 + threadIdx.x;
  const int stride = gridDim.x * 256;
  for (; i < n4; i += stride) {
    float4 f = ((const float4*)in)[i];
    ushort4 u = make_ushort4(f2bf(f.x), f2bf(f.y), f2bf(f.z), f2bf(f.w));
    ((ushort4*)out)[i] = u;
  }
}

// ---------- W[K,N] fp32 -> Wt[N,K] bf16 (optionally scaled) ----------
__global__ __launch_bounds__(256)
void cvt_w_t(const float* __restrict__ W, unsigned short* __restrict__ Wt,
             int K, int N, float scale)
{
  __shared__ float T[64][65];
  const int tid = threadIdx.x;
  const int n0 = blockIdx.x * 64, k0 = blockIdx.y * 64;
  #pragma unroll
  for (int it = 0; it < 4; ++it) {
    int kr = (tid >> 4) + it * 16;
    float4 f = *(const float4*)(W + (size_t)(k0 + kr) * N + n0 + (tid & 15) * 4);
    T[kr][(tid & 15) * 4 + 0] = f.x;
    T[kr][(tid & 15) * 4 + 1] = f.y;
    T[kr][(tid & 15) * 4 + 2] = f.z;
    T[kr][(tid & 15) * 4 + 3] = f.w;
  }
  __syncthreads();
  #pragma unroll
  for (int it = 0; it < 4; ++it) {
    int nr = (tid >> 4) + it * 16;
    int c0 = (tid & 15) * 4;
    ushort4 u = make_ushort4(f2bf(T[c0 + 0][nr] * scale), f2bf(T[c0 + 1][nr] * scale),
                             f2bf(T[c0 + 2][nr] * scale), f2bf(T[c0 + 3][nr] * scale));
    *(ushort4*)(Wt + (size_t)(n0 + nr) * K + k0 + c0) = u;
  }
}

// ---------- bf16 MFMA GEMM: C[M,N] = A[M,1024] @ Wt[N,1024]^T ----------
// EPI: 0 = store bf16; 2 = silu(x+bias[col]) store bf16; 3 = store fp32
template<int EPI>
__global__ __launch_bounds__(256)
void gemm_bf16(const unsigned short* __restrict__ A,
               const unsigned short* __restrict__ Bt,
               const float* __restrict__ bias,
               void* __restrict__ Cout, int N)
{
  __shared__ unsigned short As[2][128 * 32];
  __shared__ unsigned short Bs[2][128 * 32];
  const int tid = threadIdx.x;
  const int w = tid >> 6, l = tid & 63;
  const int wr = w >> 1, wc = w & 1;
  const int m0 = blockIdx.y * 128, n0 = blockIdx.x * 128;

  const unsigned short* gA[2];
  const unsigned short* gB[2];
  #pragma unroll
  for (int i = 0; i < 2; ++i) {
    int p = (i * 256 + tid) * 16;
    int L = p ^ (((p >> 7) & 3) << 4);
    int r = L >> 6;
    int ke = (L & 63) >> 1;
    gA[i] = A  + (size_t)(m0 + r) * 1024 + ke;
    gB[i] = Bt + (size_t)(n0 + r) * 1024 + ke;
  }
  int pA[4], pB[4];
  #pragma unroll
  for (int f = 0; f < 4; ++f) {
    int rA = wr * 64 + f * 16 + (l & 15);
    int LA = rA * 64 + (l >> 4) * 16;
    pA[f] = LA ^ (((LA >> 7) & 3) << 4);
    int rB = wc * 64 + f * 16 + (l & 15);
    int LB = rB * 64 + (l >> 4) * 16;
    pB[f] = LB ^ (((LB >> 7) & 3) << 4);
  }

  f32x4 acc[4][4];
  #pragma unroll
  for (int i = 0; i < 4; ++i)
    #pragma unroll
    for (int j = 0; j < 4; ++j)
      acc[i][j] = (f32x4){0.f, 0.f, 0.f, 0.f};

  #pragma unroll
  for (int i = 0; i < 2; ++i) {
    gload_lds16(gA[i], &As[0][(i * 256 + w * 64) * 8]);
    gload_lds16(gB[i], &Bs[0][(i * 256 + w * 64) * 8]);
  }
  __syncthreads();

  int buf = 0;
  for (int ks = 0; ks < 32; ++ks) {
    if (ks < 31) {
      const int k0 = (ks + 1) * 32;
      #pragma unroll
      for (int i = 0; i < 2; ++i) {
        gload_lds16(gA[i] + k0, &As[buf ^ 1][(i * 256 + w * 64) * 8]);
        gload_lds16(gB[i] + k0, &Bs[buf ^ 1][(i * 256 + w * 64) * 8]);
      }
    }
    short8 av[4], bv[4];
    #pragma unroll
    for (int f = 0; f < 4; ++f) {
      av[f] = *(const short8*)((const char*)&As[buf][0] + pA[f]);
      bv[f] = *(const short8*)((const char*)&Bs[buf][0] + pB[f]);
    }
    #pragma unroll
    for (int fi = 0; fi < 4; ++fi)
      #pragma unroll
      for (int fj = 0; fj < 4; ++fj)
        acc[fi][fj] = __builtin_amdgcn_mfma_f32_16x16x32_bf16(
            av[fi], bv[fj], acc[fi][fj], 0, 0, 0);
    __syncthreads();
    buf ^= 1;
  }

  const int cr = (l >> 4) * 4;
  const int cc = l & 15;
  #pragma unroll
  for (int fi = 0; fi < 4; ++fi) {
    #pragma unroll
    for (int fj = 0; fj < 4; ++fj) {
      int row = m0 + wr * 64 + fi * 16 + cr;
      int col = n0 + wc * 64 + fj * 16 + cc;
      float bcol = (EPI == 2) ? bias[col] : 0.f;
      #pragma unroll
      for (int j = 0; j < 4; ++j) {
        float x = acc[fi][fj][j];
        if (EPI == 2) {
          float z = x + bcol;
          x = z / (1.f + expf(-z));
        }
        if (EPI == 3)
          ((float*)Cout)[(size_t)(row + j) * N + col] = x;
        else
          ((unsigned short*)Cout)[(size_t)(row + j) * N + col] = f2bf(x);
      }
    }
  }
}

// ---------------- t1 = x[M,1024] @ Wg1[1024,16] (fp32) ----------------
__global__ __launch_bounds__(256)
void gemm_g1(const float* __restrict__ x, const float* __restrict__ W1,
             float* __restrict__ t1)
{
  __shared__ float Xs[16][64];
  __shared__ float Ws[64][16];
  const int tid = threadIdx.x;
  const int m0 = blockIdx.x * 16;
  const int mi = tid >> 4, n = tid & 15;
  float acc = 0.f;
  for (int k0 = 0; k0 < 1024; k0 += 64) {
    *(float4*)&Xs[tid >> 4][(tid & 15) * 4] =
        *(const float4*)(x + (size_t)(m0 + (tid >> 4)) * 1024 + k0 + (tid & 15) * 4);
    *(float4*)&Ws[tid >> 2][(tid & 3) * 4] =
        *(const float4*)(W1 + (size_t)(k0 + (tid >> 2)) * 16 + (tid & 3) * 4);
    __syncthreads();
    #pragma unroll
    for (int kk = 0; kk < 64; ++kk)
      acc = fmaf(Xs[mi][kk], Ws[kk][n], acc);
    __syncthreads();
  }
  t1[(size_t)(m0 + mi) * 16 + n] = acc;
}

// --------- lg = log_sigmoid(t1 @ Wg2) / 16,  [M, 512] fp32 ---------
__global__ __launch_bounds__(256)
void gemm_g2(const float* __restrict__ t1, const float* __restrict__ W2,
             float* __restrict__ lg)
{
  const int idx = blockIdx.x * 256 + threadIdx.x;
  const int m = idx >> 9, n = idx & 511;
  float acc = 0.f;
  #pragma unroll
  for (int kk = 0; kk < 16; ++kk)
    acc = fmaf(t1[m * 16 + kk], W2[kk * 512 + n], acc);
  float ls = fminf(acc, 0.f) - log1pf(expf(-fabsf(acc)));
  lg[idx] = ls * 0.0625f;
}

// ============ chunked GLA — MFMA version ============
// chunk_state: P[e][d] = sum_t v[t][e] * (k[t][d] exp(Lsum_d - Lcum_t,d));
// Dd[d] = exp(Lsum_d). P stored [e=64][d=32] per (bh,chunk).
__global__ __launch_bounds__(256)
void gla_chunk_state(const unsigned short* __restrict__ k, const float* __restrict__ lg,
                     const unsigned short* __restrict__ v, float* __restrict__ P,
                     float* __restrict__ Dd)
{
  __shared__ __align__(16) float Lc[CHK][32];            // 8 KB
  __shared__ __align__(16) unsigned short kdT[32][72];   // k'' transposed [d][t]
  __shared__ __align__(16) unsigned short vT[64][72];    // v transposed [e][t]
  const int blk = blockIdx.x;
  const int bh = blk >> 6, chunk = blk & (NCHK - 1);
  const int b = bh >> 4, h = bh & 15;
  const int tid = threadIdx.x;
  const int w = tid >> 6, l = tid & 63;
  const size_t rowq = ((size_t)b * Lq + (size_t)chunk * CHK) * 512 + h * 32;
  const size_t rowv = ((size_t)b * Lq + (size_t)chunk * CHK) * 1024 + h * 64;

  #pragma unroll
  for (int r = 0; r < 2; ++r) {
    int s4 = (tid + 256 * r) * 4;
    int t = s4 >> 5, d0 = s4 & 31;
    *(float4*)&Lc[t][d0] = *(const float4*)(lg + rowq + (size_t)t * 512 + d0);
  }
  __syncthreads();
  if (tid < 32) {
    float s = 0.f;
    for (int t = 0; t < CHK; ++t) { s += Lc[t][tid]; Lc[t][tid] = s; }
  }
  __syncthreads();
  // k'' transposed into [d][t]
  #pragma unroll
  for (int r = 0; r < 2; ++r) {
    int s4 = (tid + 256 * r) * 4;
    int t = s4 >> 5, d0 = s4 & 31;
    ushort4 kv = *(const ushort4*)(k + rowq + (size_t)t * 512 + d0);
    float4 lc = *(const float4*)&Lc[t][d0];
    float4 ls = *(const float4*)&Lc[CHK - 1][d0];
    kdT[d0 + 0][t] = f2bf(bf2f(kv.x) * expf(ls.x - lc.x));
    kdT[d0 + 1][t] = f2bf(bf2f(kv.y) * expf(ls.y - lc.y));
    kdT[d0 + 2][t] = f2bf(bf2f(kv.z) * expf(ls.z - lc.z));
    kdT[d0 + 3][t] = f2bf(bf2f(kv.w) * expf(ls.w - lc.w));
  }
  // v transposed into [e][t]
  #pragma unroll
  for (int r = 0; r < 4; ++r) {
    int s4 = (tid + 256 * r) * 4;
    int t = s4 >> 6, e0 = s4 & 63;
    ushort4 vv = *(const ushort4*)(v + rowv + (size_t)t * 1024 + e0);
    vT[e0 + 0][t] = vv.x;
    vT[e0 + 1][t] = vv.y;
    vT[e0 + 2][t] = vv.z;
    vT[e0 + 3][t] = vv.w;
  }
  __syncthreads();
  // wave w owns e-block w: P[16w..16w+15][*]
  #pragma unroll
  for (int dj = 0; dj < 2; ++dj) {
    f32x4 acc = (f32x4){0.f, 0.f, 0.f, 0.f};
    #pragma unroll
    for (int ks = 0; ks < 2; ++ks) {
      short8 aV = *(const short8*)((const char*)&vT[0][0] +
                    (16 * w + (l & 15)) * 144 + ks * 64 + (l >> 4) * 16);
      short8 bK = *(const short8*)((const char*)&kdT[0][0] +
                    (16 * dj + (l & 15)) * 144 + ks * 64 + (l >> 4) * 16);
      acc = __builtin_amdgcn_mfma_f32_16x16x32_bf16(aV, bK, acc, 0, 0, 0);
    }
    #pragma unroll
    for (int j = 0; j < 4; ++j) {
      int e = 16 * w + (l >> 4) * 4 + j;
      int d = 16 * dj + (l & 15);
      P[(size_t)blk * 2048 + e * 32 + d] = acc[j];
    }
  }
  if (tid < 32) Dd[(size_t)blk * 32 + tid] = expf(Lc[CHK - 1][tid]);
}

// chain over chunks per bh; P layout [e][d] -> d = idx & 31
__global__ __launch_bounds__(256)
void gla_chain(float* __restrict__ P, const float* __restrict__ Dd)
{
  const int bh = blockIdx.x;
  const int tid = threadIdx.x;
  float4 sA = {0.f, 0.f, 0.f, 0.f}, sB = {0.f, 0.f, 0.f, 0.f};
  const int fA = tid * 4, fB = tid * 4 + 1024;
  const int d0 = fA & 31;
  for (int i = 0; i < NCHK; ++i) {
    const size_t base = ((size_t)bh * NCHK + i) * 2048;
    float4 dd = *(const float4*)(Dd + ((size_t)bh * NCHK + i) * 32 + d0);
    float4 pa = *(const float4*)(P + base + fA);
    float4 pb = *(const float4*)(P + base + fB);
    *(float4*)(P + base + fA) = sA;
    *(float4*)(P + base + fB) = sB;
    sA.x = fmaf(sA.x, dd.x, pa.x); sA.y = fmaf(sA.y, dd.y, pa.y);
    sA.z = fmaf(sA.z, dd.z, pa.z); sA.w = fmaf(sA.w, dd.w, pa.w);
    sB.x = fmaf(sB.x, dd.x, pb.x); sB.y = fmaf(sB.y, dd.y, pb.y);
    sB.z = fmaf(sB.z, dd.z, pb.z); sB.w = fmaf(sB.w, dd.w, pb.w);
  }
}

// chunk_out (MFMA):
//   A = tril(q' kd^T)  (64x64, K=32), o = A @ v + q' @ S^T
// wave w owns t-row-block w.
__global__ __launch_bounds__(256)
void gla_chunk_out(const unsigned short* __restrict__ q, const unsigned short* __restrict__ k,
                   const float* __restrict__ lg, const unsigned short* __restrict__ v,
                   const float* __restrict__ S, float* __restrict__ o)
{
  __shared__ __align__(16) float Lc[CHK][32];            // 8192
  __shared__ __align__(16) unsigned short qb[CHK][40];   // q' [t][d]   5120
  __shared__ __align__(16) unsigned short kd[CHK][40];   // k'' [s][d]  5120
  __shared__ __align__(16) unsigned short vT[64][72];    // v^T [e][s]  9216
  __shared__ __align__(16) unsigned short ST[64][40];    // S^T [e][d]  5120
  __shared__ __align__(16) unsigned short Aq[64][72];    // A [t][s]    9216
  const int blk = blockIdx.x;
  const int bh = blk >> 6, chunk = blk & (NCHK - 1);
  const int b = bh >> 4, h = bh & 15;
  const int tid = threadIdx.x;
  const int w = tid >> 6, l = tid & 63;
  const size_t rowq = ((size_t)b * Lq + (size_t)chunk * CHK) * 512 + h * 32;
  const size_t rowv = ((size_t)b * Lq + (size_t)chunk * CHK) * 1024 + h * 64;

  #pragma unroll
  for (int r = 0; r < 2; ++r) {
    int s4 = (tid + 256 * r) * 4;
    int t = s4 >> 5, d0 = s4 & 31;
    *(float4*)&Lc[t][d0] = *(const float4*)(lg + rowq + (size_t)t * 512 + d0);
  }
  __syncthreads();
  if (tid < 32) {
    float s = 0.f;
    for (int t = 0; t < CHK; ++t) { s += Lc[t][tid]; Lc[t][tid] = s; }
  }
  __syncthreads();
  // q' = q*exp(Lcum); k'' = k*exp(-Lcum)
  #pragma unroll
  for (int r = 0; r < 2; ++r) {
    int s4 = (tid + 256 * r) * 4;
    int t = s4 >> 5, d0 = s4 & 31;
    ushort4 kv = *(const ushort4*)(k + rowq + (size_t)t * 512 + d0);
    ushort4 qv = *(const ushort4*)(q + rowq + (size_t)t * 512 + d0);
    float4 lc = *(const float4*)&Lc[t][d0];
    ushort4 ko, qo;
    ko.x = f2bf(bf2f(kv.x) * expf(-lc.x)); qo.x = f2bf(bf2f(qv.x) * expf(lc.x));
    ko.y = f2bf(bf2f(kv.y) * expf(-lc.y)); qo.y = f2bf(bf2f(qv.y) * expf(lc.y));
    ko.z = f2bf(bf2f(kv.z) * expf(-lc.z)); qo.z = f2bf(bf2f(qv.z) * expf(lc.z));
    ko.w = f2bf(bf2f(kv.w) * expf(-lc.w)); qo.w = f2bf(bf2f(qv.w) * expf(lc.w));
    *(ushort4*)&kd[t][d0] = ko;
    *(ushort4*)&qb[t][d0] = qo;
  }
  // v^T
  #pragma unroll
  for (int r = 0; r < 4; ++r) {
    int s4 = (tid + 256 * r) * 4;
    int t = s4 >> 6, e0 = s4 & 63;
    ushort4 vv = *(const ushort4*)(v + rowv + (size_t)t * 1024 + e0);
    vT[e0 + 0][t] = vv.x;
    vT[e0 + 1][t] = vv.y;
    vT[e0 + 2][t] = vv.z;
    vT[e0 + 3][t] = vv.w;
  }
  // S^T: S stored [e][d] already -> linear copy + cvt
  #pragma unroll
  for (int r = 0; r < 2; ++r) {
    int s4 = (tid + 256 * r) * 4;
    int e = s4 >> 5, d0 = s4 & 31;
    float4 f = *(const float4*)(S + (size_t)blk * 2048 + s4);
    ushort4 u = make_ushort4(f2bf(f.x), f2bf(f.y), f2bf(f.z), f2bf(f.w));
    *(ushort4*)&ST[e][d0] = u;
  }
  __syncthreads();

  // ---- QK^T: wave w computes A rows [16w,16w+16) ----
  short8 aQ = *(const short8*)((const char*)&qb[0][0] +
               (16 * w + (l & 15)) * 80 + (l >> 4) * 16);
  const int tl0 = (l >> 4) * 4;     // acc row base (t_local)
  #pragma unroll
  for (int si = 0; si < 4; ++si) {
    if (si <= w) {
      short8 bK = *(const short8*)((const char*)&kd[0][0] +
                   (16 * si + (l & 15)) * 80 + (l >> 4) * 16);
      f32x4 acc = (f32x4){0.f, 0.f, 0.f, 0.f};
      acc = __builtin_amdgcn_mfma_f32_16x16x32_bf16(aQ, bK, acc, 0, 0, 0);
      #pragma unroll
      for (int j = 0; j < 4; ++j) {
        bool keep = (si < w) || ((l & 15) <= tl0 + j);
        Aq[16 * w + tl0 + j][16 * si + (l & 15)] = keep ? f2bf(acc[j]) : 0;
      }
    } else {
      #pragma unroll
      for (int j = 0; j < 4; ++j)
        Aq[16 * w + tl0 + j][16 * si + (l & 15)] = 0;
    }
  }
  __syncthreads();

  // ---- o = A @ v + q' @ S^T : wave w does t-block w, all 4 e-blocks ----
  short8 aA0 = *(const short8*)((const char*)&Aq[0][0] +
                (16 * w + (l & 15)) * 144 + (l >> 4) * 16);
  short8 aA1 = *(const short8*)((const char*)&Aq[0][0] +
                (16 * w + (l & 15)) * 144 + 64 + (l >> 4) * 16);
  const size_t obase = ((size_t)b * Lq + (size_t)chunk * CHK) * 1024 + h * 64;
  #pragma unroll
  for (int ej = 0; ej < 4; ++ej) {
    f32x4 acc = (f32x4){0.f, 0.f, 0.f, 0.f};
    short8 bV0 = *(const short8*)((const char*)&vT[0][0] +
                  (16 * ej + (l & 15)) * 144 + (l >> 4) * 16);
    short8 bV1 = *(const short8*)((const char*)&vT[0][0] +
                  (16 * ej + (l & 15)) * 144 + 64 + (l >> 4) * 16);
    short8 bS = *(const short8*)((const char*)&ST[0][0] +
                  (16 * ej + (l & 15)) * 80 + (l >> 4) * 16);
    acc = __builtin_amdgcn_mfma_f32_16x16x32_bf16(aA0, bV0, acc, 0, 0, 0);
    acc = __builtin_amdgcn_mfma_f32_16x16x32_bf16(aA1, bV1, acc, 0, 0, 0);
    acc = __builtin_amdgcn_mfma_f32_16x16x32_bf16(aQ,  bS,  acc, 0, 0, 0);
    #pragma unroll
    for (int j = 0; j < 4; ++j) {
      int t = 16 * w + tl0 + j;
      int e = 16 * ej + (l & 15);
      o[obase + (size_t)t * 1024 + e] = acc[j];
    }
  }
}

// --------- group norm + gate multiply -> bf16 A-operand ---------
__global__ __launch_bounds__(256)
void gnorm_gate(const float* __restrict__ o, const unsigned short* __restrict__ gate,
                unsigned short* __restrict__ gated)
{
  const int gid = blockIdx.x * 4 + (threadIdx.x >> 6);
  const int e = threadIdx.x & 63;
  const size_t addr = (size_t)gid * 64 + e;
  float val = o[addr];
  float s = val;
  #pragma unroll
  for (int m = 32; m; m >>= 1) s += __shfl_xor(s, m, 64);
  float mean = s * (1.f / 64.f);
  float d = val - mean;
  float s2 = d * d;
  #pragma unroll
  for (int m = 32; m; m >>= 1) s2 += __shfl_xor(s2, m, 64);
  float y = d * rsqrtf(s2 * (1.f / 64.f) + kEps);
  gated[addr] = f2bf(bf2f(gate[addr]) * y);
}

} // namespace

extern "C" void kernel_launch(void* const* d_in, const int* in_sizes, int n_in,
                              void* d_out, int out_size, void* d_ws, size_t ws_size,
                              hipStream_t stream)
{
  (void)in_sizes; (void)n_in; (void)out_size; (void)ws_size;
  const float* x   = (const float*)d_in[0];
  const float* Wq  = (const float*)d_in[1];
  const float* Wk  = (const float*)d_in[2];
  const float* Wg1 = (const float*)d_in[3];
  const float* Wg2 = (const float*)d_in[4];
  const float* Wv  = (const float*)d_in[5];
  const float* Wg  = (const float*)d_in[6];
  const float* bg  = (const float*)d_in[7];
  const float* Wo  = (const float*)d_in[8];

  // workspace: 177.7 MB total
  char* w = (char*)d_ws;
  unsigned short* xh  = (unsigned short*)w; w += (size_t)Mrows * 1024 * 2;
  unsigned short* qh  = (unsigned short*)w; w += (size_t)Mrows * 512 * 2;
  unsigned short* kh  = (unsigned short*)w; w += (size_t)Mrows * 512 * 2;
  unsigned short* vh  = (unsigned short*)w; w += (size_t)Mrows * 1024 * 2;
  float*  lgb = (float*)w;                  w += (size_t)Mrows * 512 * 4;
  float*  t1  = (float*)w;                  w += (size_t)Mrows * 16 * 4;
  float*  Pst = (float*)w;                  w += (size_t)64 * NCHK * 2048 * 4;
  float*  Dd  = (float*)w;                  w += (size_t)64 * NCHK * 32 * 4;
  unsigned short* Wqt = (unsigned short*)w; w += (size_t)512 * 1024 * 2;
  unsigned short* Wkt = (unsigned short*)w; w += (size_t)512 * 1024 * 2;
  unsigned short* Wvt = (unsigned short*)w; w += (size_t)1024 * 1024 * 2;
  unsigned short* Wgt = (unsigned short*)w; w += (size_t)1024 * 1024 * 2;
  unsigned short* Wot = (unsigned short*)w; w += (size_t)1024 * 1024 * 2;
  unsigned short* gateh  = qh;                    // alias over qh+kh
  unsigned short* gatedh = (unsigned short*)lgb;  // alias over lgb

  // dtype conversions
  cvt_bf16<<<2048, 256, 0, stream>>>(x, xh, Mrows * 1024 / 4);
  cvt_w_t<<<dim3(8, 16),  256, 0, stream>>>(Wq, Wqt, 1024, 512, 1.f);
  cvt_w_t<<<dim3(8, 16),  256, 0, stream>>>(Wk, Wkt, 1024, 512, kScale);
  cvt_w_t<<<dim3(16, 16), 256, 0, stream>>>(Wv, Wvt, 1024, 1024, 1.f);
  cvt_w_t<<<dim3(16, 16), 256, 0, stream>>>(Wg, Wgt, 1024, 1024, 1.f);
  cvt_w_t<<<dim3(16, 16), 256, 0, stream>>>(Wo, Wot, 1024, 1024, 1.f);
  // projections (MFMA)
  gemm_bf16<0><<<dim3(4, 128), 256, 0, stream>>>(xh, Wqt, nullptr, qh, 512);
  gemm_bf16<0><<<dim3(4, 128), 256, 0, stream>>>(xh, Wkt, nullptr, kh, 512);
  gemm_bf16<0><<<dim3(8, 128), 256, 0, stream>>>(xh, Wvt, nullptr, vh, 1024);
  gemm_g1<<<Mrows / 16, 256, 0, stream>>>(x, Wg1, t1);
  gemm_g2<<<(Mrows * 512) / 256, 256, 0, stream>>>(t1, Wg2, lgb);
  // chunked recurrence (MFMA)
  gla_chunk_state<<<64 * NCHK, 256, 0, stream>>>(kh, lgb, vh, Pst, Dd);
  gla_chain<<<64, 256, 0, stream>>>(Pst, Dd);
  gla_chunk_out<<<64 * NCHK, 256, 0, stream>>>(qh, kh, lgb, vh, Pst, (float*)d_out);
  // gate path (qh/kh now dead -> gateh alias)
  gemm_bf16<2><<<dim3(8, 128), 256, 0, stream>>>(xh, Wgt, bg, gateh, 1024);
  gnorm_gate<<<(Mrows * H_) / 4, 256, 0, stream>>>((const float*)d_out, gateh, gatedh);
  // output projection
  gemm_bf16<3><<<dim3(8, 128), 256, 0, stream>>>(gatedh, Wot, nullptr, d_out, 1024);
}

// Round 6
// 451.371 us; speedup vs baseline: 23.1762x; 1.0693x over previous
//
#include <hip/hip_runtime.h>
#include <cstdint>

namespace {

constexpr int Lq  = 4096;
constexpr int Bq  = 4;
constexpr int H_  = 16;
constexpr int Mrows = Bq * Lq;               // 16384
constexpr int CHK  = 64;
constexpr int NCHK = Lq / CHK;               // 64
constexpr int QKVS = 2048;                   // fused qkv row stride
constexpr float kScale = 0.17677669529663687f;  // 32^-0.5
constexpr float kEps   = 1e-5f;

typedef __attribute__((ext_vector_type(8))) short short8;
typedef __attribute__((ext_vector_type(4))) float f32x4;

__device__ __forceinline__ float bf2f(unsigned short u) {
  return __uint_as_float(((unsigned)u) << 16);
}
__device__ __forceinline__ unsigned short f2bf(float f) {
  unsigned u = __float_as_uint(f);
  u += 0x7fffu + ((u >> 16) & 1u);   // RNE
  return (unsigned short)(u >> 16);
}
__device__ __forceinline__ void gload_lds16(const void* g, void* l) {
  __builtin_amdgcn_global_load_lds(
      (const __attribute__((address_space(1))) void*)g,
      (__attribute__((address_space(3))) void*)l, 16, 0, 0);
}

// ---------- x fp32 -> bf16 ----------
__global__ __launch_bounds__(256)
void cvt_bf16(const float* __restrict__ in, unsigned short* __restrict__ out, int n4)
{
  int i = blockIdx.x * 256 + threadIdx.x;
  const int stride = gridDim.x * 256;
  for (; i < n4; i += stride) {
    float4 f = ((const float4*)in)[i];
    ushort4 u = make_ushort4(f2bf(f.x), f2bf(f.y), f2bf(f.z), f2bf(f.w));
    ((ushort4*)out)[i] = u;
  }
}

// ---------- W[K,N] fp32 -> Wt[N,K] bf16 (optionally scaled) ----------
__global__ __launch_bounds__(256)
void cvt_w_t(const float* __restrict__ W, unsigned short* __restrict__ Wt,
             int K, int N, float scale)
{
  __shared__ float T[64][65];
  const int tid = threadIdx.x;
  const int n0 = blockIdx.x * 64, k0 = blockIdx.y * 64;
  #pragma unroll
  for (int it = 0; it < 4; ++it) {
    int kr = (tid >> 4) + it * 16;
    float4 f = *(const float4*)(W + (size_t)(k0 + kr) * N + n0 + (tid & 15) * 4);
    T[kr][(tid & 15) * 4 + 0] = f.x;
    T[kr][(tid & 15) * 4 + 1] = f.y;
    T[kr][(tid & 15) * 4 + 2] = f.z;
    T[kr][(tid & 15) * 4 + 3] = f.w;
  }
  __syncthreads();
  #pragma unroll
  for (int it = 0; it < 4; ++it) {
    int nr = (tid >> 4) + it * 16;
    int c0 = (tid & 15) * 4;
    ushort4 u = make_ushort4(f2bf(T[c0 + 0][nr] * scale), f2bf(T[c0 + 1][nr] * scale),
                             f2bf(T[c0 + 2][nr] * scale), f2bf(T[c0 + 3][nr] * scale));
    *(ushort4*)(Wt + (size_t)(n0 + nr) * K + k0 + c0) = u;
  }
}

// ---------- bf16 MFMA GEMM: C[M,N] = A[M,1024] @ Wt[N,1024]^T ----------
// XCD-aware bijective swizzle (requires nwg % 8 == 0), bn-fastest decode so
// each XCD owns contiguous M-panels (A-panel fetched once per XCD group).
// EPI: 0 = store bf16; 2 = silu(x+bias[col]) store bf16; 3 = store fp32
template<int EPI>
__global__ __launch_bounds__(256)
void gemm_bf16(const unsigned short* __restrict__ A,
               const unsigned short* __restrict__ Bt,
               const float* __restrict__ bias,
               void* __restrict__ Cout, int N)
{
  __shared__ unsigned short As[2][128 * 32];
  __shared__ unsigned short Bs[2][128 * 32];
  const int tid = threadIdx.x;
  const int w = tid >> 6, l = tid & 63;
  const int wr = w >> 1, wc = w & 1;

  const int nbx = gridDim.x;
  const int bid = blockIdx.y * nbx + blockIdx.x;
  const int cpx = (nbx * gridDim.y) >> 3;
  const int swz = (bid & 7) * cpx + (bid >> 3);
  const int m0 = (swz / nbx) * 128, n0 = (swz % nbx) * 128;

  const unsigned short* gA[2];
  const unsigned short* gB[2];
  #pragma unroll
  for (int i = 0; i < 2; ++i) {
    int p = (i * 256 + tid) * 16;
    int L = p ^ (((p >> 7) & 3) << 4);
    int r = L >> 6;
    int ke = (L & 63) >> 1;
    gA[i] = A  + (size_t)(m0 + r) * 1024 + ke;
    gB[i] = Bt + (size_t)(n0 + r) * 1024 + ke;
  }
  int pA[4], pB[4];
  #pragma unroll
  for (int f = 0; f < 4; ++f) {
    int rA = wr * 64 + f * 16 + (l & 15);
    int LA = rA * 64 + (l >> 4) * 16;
    pA[f] = LA ^ (((LA >> 7) & 3) << 4);
    int rB = wc * 64 + f * 16 + (l & 15);
    int LB = rB * 64 + (l >> 4) * 16;
    pB[f] = LB ^ (((LB >> 7) & 3) << 4);
  }

  f32x4 acc[4][4];
  #pragma unroll
  for (int i = 0; i < 4; ++i)
    #pragma unroll
    for (int j = 0; j < 4; ++j)
      acc[i][j] = (f32x4){0.f, 0.f, 0.f, 0.f};

  #pragma unroll
  for (int i = 0; i < 2; ++i) {
    gload_lds16(gA[i], &As[0][(i * 256 + w * 64) * 8]);
    gload_lds16(gB[i], &Bs[0][(i * 256 + w * 64) * 8]);
  }
  __syncthreads();

  int buf = 0;
  for (int ks = 0; ks < 32; ++ks) {
    if (ks < 31) {
      const int k0 = (ks + 1) * 32;
      #pragma unroll
      for (int i = 0; i < 2; ++i) {
        gload_lds16(gA[i] + k0, &As[buf ^ 1][(i * 256 + w * 64) * 8]);
        gload_lds16(gB[i] + k0, &Bs[buf ^ 1][(i * 256 + w * 64) * 8]);
      }
    }
    short8 av[4], bv[4];
    #pragma unroll
    for (int f = 0; f < 4; ++f) {
      av[f] = *(const short8*)((const char*)&As[buf][0] + pA[f]);
      bv[f] = *(const short8*)((const char*)&Bs[buf][0] + pB[f]);
    }
    #pragma unroll
    for (int fi = 0; fi < 4; ++fi)
      #pragma unroll
      for (int fj = 0; fj < 4; ++fj)
        acc[fi][fj] = __builtin_amdgcn_mfma_f32_16x16x32_bf16(
            av[fi], bv[fj], acc[fi][fj], 0, 0, 0);
    __syncthreads();
    buf ^= 1;
  }

  const int cr = (l >> 4) * 4;
  const int cc = l & 15;
  #pragma unroll
  for (int fi = 0; fi < 4; ++fi) {
    #pragma unroll
    for (int fj = 0; fj < 4; ++fj) {
      int row = m0 + wr * 64 + fi * 16 + cr;
      int col = n0 + wc * 64 + fj * 16 + cc;
      float bcol = (EPI == 2) ? bias[col] : 0.f;
      #pragma unroll
      for (int j = 0; j < 4; ++j) {
        float x = acc[fi][fj][j];
        if (EPI == 2) {
          float z = x + bcol;
          x = z / (1.f + expf(-z));
        }
        if (EPI == 3)
          ((float*)Cout)[(size_t)(row + j) * N + col] = x;
        else
          ((unsigned short*)Cout)[(size_t)(row + j) * N + col] = f2bf(x);
      }
    }
  }
}

// ---------------- t1 = x[M,1024] @ Wg1[1024,16] (fp32) ----------------
__global__ __launch_bounds__(256)
void gemm_g1(const float* __restrict__ x, const float* __restrict__ W1,
             float* __restrict__ t1)
{
  __shared__ float Xs[16][64];
  __shared__ float Ws[64][16];
  const int tid = threadIdx.x;
  const int m0 = blockIdx.x * 16;
  const int mi = tid >> 4, n = tid & 15;
  float acc = 0.f;
  for (int k0 = 0; k0 < 1024; k0 += 64) {
    *(float4*)&Xs[tid >> 4][(tid & 15) * 4] =
        *(const float4*)(x + (size_t)(m0 + (tid >> 4)) * 1024 + k0 + (tid & 15) * 4);
    *(float4*)&Ws[tid >> 2][(tid & 3) * 4] =
        *(const float4*)(W1 + (size_t)(k0 + (tid >> 2)) * 16 + (tid & 3) * 4);
    __syncthreads();
    #pragma unroll
    for (int kk = 0; kk < 64; ++kk)
      acc = fmaf(Xs[mi][kk], Ws[kk][n], acc);
    __syncthreads();
  }
  t1[(size_t)(m0 + mi) * 16 + n] = acc;
}

// --------- lg = log_sigmoid(t1 @ Wg2) / 16,  [M, 512] fp32 ---------
__global__ __launch_bounds__(256)
void gemm_g2(const float* __restrict__ t1, const float* __restrict__ W2,
             float* __restrict__ lg)
{
  const int idx = blockIdx.x * 256 + threadIdx.x;
  const int m = idx >> 9, n = idx & 511;
  float acc = 0.f;
  #pragma unroll
  for (int kk = 0; kk < 16; ++kk)
    acc = fmaf(t1[m * 16 + kk], W2[kk * 512 + n], acc);
  float ls = fminf(acc, 0.f) - log1pf(expf(-fabsf(acc)));
  lg[idx] = ls * 0.0625f;
}

// ============ chunked GLA — MFMA version (fused qkv input) ============
// qkv[M][2048]: cols [0,512)=q, [512,1024)=k, [1024,2048)=v
__global__ __launch_bounds__(256)
void gla_chunk_state(const unsigned short* __restrict__ qkv, const float* __restrict__ lg,
                     float* __restrict__ P, float* __restrict__ Dd)
{
  __shared__ __align__(16) float Lc[CHK][32];
  __shared__ __align__(16) unsigned short kdT[32][72];
  __shared__ __align__(16) unsigned short vT[64][72];
  const int blk = blockIdx.x;
  const int bh = blk >> 6, chunk = blk & (NCHK - 1);
  const int b = bh >> 4, h = bh & 15;
  const int tid = threadIdx.x;
  const int w = tid >> 6, l = tid & 63;
  const size_t rbase = ((size_t)b * Lq + (size_t)chunk * CHK) * QKVS;
  const size_t rowk = rbase + 512 + h * 32;
  const size_t rowv = rbase + 1024 + h * 64;
  const size_t rowl = ((size_t)b * Lq + (size_t)chunk * CHK) * 512 + h * 32;

  #pragma unroll
  for (int r = 0; r < 2; ++r) {
    int s4 = (tid + 256 * r) * 4;
    int t = s4 >> 5, d0 = s4 & 31;
    *(float4*)&Lc[t][d0] = *(const float4*)(lg + rowl + (size_t)t * 512 + d0);
  }
  __syncthreads();
  if (tid < 32) {
    float s = 0.f;
    for (int t = 0; t < CHK; ++t) { s += Lc[t][tid]; Lc[t][tid] = s; }
  }
  __syncthreads();
  #pragma unroll
  for (int r = 0; r < 2; ++r) {
    int s4 = (tid + 256 * r) * 4;
    int t = s4 >> 5, d0 = s4 & 31;
    ushort4 kv = *(const ushort4*)(qkv + rowk + (size_t)t * QKVS + d0);
    float4 lc = *(const float4*)&Lc[t][d0];
    float4 ls = *(const float4*)&Lc[CHK - 1][d0];
    kdT[d0 + 0][t] = f2bf(bf2f(kv.x) * expf(ls.x - lc.x));
    kdT[d0 + 1][t] = f2bf(bf2f(kv.y) * expf(ls.y - lc.y));
    kdT[d0 + 2][t] = f2bf(bf2f(kv.z) * expf(ls.z - lc.z));
    kdT[d0 + 3][t] = f2bf(bf2f(kv.w) * expf(ls.w - lc.w));
  }
  #pragma unroll
  for (int r = 0; r < 4; ++r) {
    int s4 = (tid + 256 * r) * 4;
    int t = s4 >> 6, e0 = s4 & 63;
    ushort4 vv = *(const ushort4*)(qkv + rowv + (size_t)t * QKVS + e0);
    vT[e0 + 0][t] = vv.x;
    vT[e0 + 1][t] = vv.y;
    vT[e0 + 2][t] = vv.z;
    vT[e0 + 3][t] = vv.w;
  }
  __syncthreads();
  #pragma unroll
  for (int dj = 0; dj < 2; ++dj) {
    f32x4 acc = (f32x4){0.f, 0.f, 0.f, 0.f};
    #pragma unroll
    for (int ks = 0; ks < 2; ++ks) {
      short8 aV = *(const short8*)((const char*)&vT[0][0] +
                    (16 * w + (l & 15)) * 144 + ks * 64 + (l >> 4) * 16);
      short8 bK = *(const short8*)((const char*)&kdT[0][0] +
                    (16 * dj + (l & 15)) * 144 + ks * 64 + (l >> 4) * 16);
      acc = __builtin_amdgcn_mfma_f32_16x16x32_bf16(aV, bK, acc, 0, 0, 0);
    }
    #pragma unroll
    for (int j = 0; j < 4; ++j) {
      int e = 16 * w + (l >> 4) * 4 + j;
      int d = 16 * dj + (l & 15);
      P[(size_t)blk * 2048 + e * 32 + d] = acc[j];
    }
  }
  if (tid < 32) Dd[(size_t)blk * 32 + tid] = expf(Lc[CHK - 1][tid]);
}

__global__ __launch_bounds__(256)
void gla_chain(float* __restrict__ P, const float* __restrict__ Dd)
{
  const int bh = blockIdx.x;
  const int tid = threadIdx.x;
  float4 sA = {0.f, 0.f, 0.f, 0.f}, sB = {0.f, 0.f, 0.f, 0.f};
  const int fA = tid * 4, fB = tid * 4 + 1024;
  const int d0 = fA & 31;
  for (int i = 0; i < NCHK; ++i) {
    const size_t base = ((size_t)bh * NCHK + i) * 2048;
    float4 dd = *(const float4*)(Dd + ((size_t)bh * NCHK + i) * 32 + d0);
    float4 pa = *(const float4*)(P + base + fA);
    float4 pb = *(const float4*)(P + base + fB);
    *(float4*)(P + base + fA) = sA;
    *(float4*)(P + base + fB) = sB;
    sA.x = fmaf(sA.x, dd.x, pa.x); sA.y = fmaf(sA.y, dd.y, pa.y);
    sA.z = fmaf(sA.z, dd.z, pa.z); sA.w = fmaf(sA.w, dd.w, pa.w);
    sB.x = fmaf(sB.x, dd.x, pb.x); sB.y = fmaf(sB.y, dd.y, pb.y);
    sB.z = fmaf(sB.z, dd.z, pb.z); sB.w = fmaf(sB.w, dd.w, pb.w);
  }
}

__global__ __launch_bounds__(256)
void gla_chunk_out(const unsigned short* __restrict__ qkv, const float* __restrict__ lg,
                   const float* __restrict__ S, float* __restrict__ o)
{
  __shared__ __align__(16) float Lc[CHK][32];
  __shared__ __align__(16) unsigned short qb[CHK][40];
  __shared__ __align__(16) unsigned short kd[CHK][40];
  __shared__ __align__(16) unsigned short vT[64][72];
  __shared__ __align__(16) unsigned short ST[64][40];
  __shared__ __align__(16) unsigned short Aq[64][72];
  const int blk = blockIdx.x;
  const int bh = blk >> 6, chunk = blk & (NCHK - 1);
  const int b = bh >> 4, h = bh & 15;
  const int tid = threadIdx.x;
  const int w = tid >> 6, l = tid & 63;
  const size_t rbase = ((size_t)b * Lq + (size_t)chunk * CHK) * QKVS;
  const size_t rowq = rbase + h * 32;
  const size_t rowk = rbase + 512 + h * 32;
  const size_t rowv = rbase + 1024 + h * 64;
  const size_t rowl = ((size_t)b * Lq + (size_t)chunk * CHK) * 512 + h * 32;

  #pragma unroll
  for (int r = 0; r < 2; ++r) {
    int s4 = (tid + 256 * r) * 4;
    int t = s4 >> 5, d0 = s4 & 31;
    *(float4*)&Lc[t][d0] = *(const float4*)(lg + rowl + (size_t)t * 512 + d0);
  }
  __syncthreads();
  if (tid < 32) {
    float s = 0.f;
    for (int t = 0; t < CHK; ++t) { s += Lc[t][tid]; Lc[t][tid] = s; }
  }
  __syncthreads();
  #pragma unroll
  for (int r = 0; r < 2; ++r) {
    int s4 = (tid + 256 * r) * 4;
    int t = s4 >> 5, d0 = s4 & 31;
    ushort4 kv = *(const ushort4*)(qkv + rowk + (size_t)t * QKVS + d0);
    ushort4 qv = *(const ushort4*)(qkv + rowq + (size_t)t * QKVS + d0);
    float4 lc = *(const float4*)&Lc[t][d0];
    ushort4 ko, qo;
    ko.x = f2bf(bf2f(kv.x) * expf(-lc.x)); qo.x = f2bf(bf2f(qv.x) * expf(lc.x));
    ko.y = f2bf(bf2f(kv.y) * expf(-lc.y)); qo.y = f2bf(bf2f(qv.y) * expf(lc.y));
    ko.z = f2bf(bf2f(kv.z) * expf(-lc.z)); qo.z = f2bf(bf2f(qv.z) * expf(lc.z));
    ko.w = f2bf(bf2f(kv.w) * expf(-lc.w)); qo.w = f2bf(bf2f(qv.w) * expf(lc.w));
    *(ushort4*)&kd[t][d0] = ko;
    *(ushort4*)&qb[t][d0] = qo;
  }
  #pragma unroll
  for (int r = 0; r < 4; ++r) {
    int s4 = (tid + 256 * r) * 4;
    int t = s4 >> 6, e0 = s4 & 63;
    ushort4 vv = *(const ushort4*)(qkv + rowv + (size_t)t * QKVS + e0);
    vT[e0 + 0][t] = vv.x;
    vT[e0 + 1][t] = vv.y;
    vT[e0 + 2][t] = vv.z;
    vT[e0 + 3][t] = vv.w;
  }
  #pragma unroll
  for (int r = 0; r < 2; ++r) {
    int s4 = (tid + 256 * r) * 4;
    int e = s4 >> 5, d0 = s4 & 31;
    float4 f = *(const float4*)(S + (size_t)blk * 2048 + s4);
    ushort4 u = make_ushort4(f2bf(f.x), f2bf(f.y), f2bf(f.z), f2bf(f.w));
    *(ushort4*)&ST[e][d0] = u;
  }
  __syncthreads();

  short8 aQ = *(const short8*)((const char*)&qb[0][0] +
               (16 * w + (l & 15)) * 80 + (l >> 4) * 16);
  const int tl0 = (l >> 4) * 4;
  #pragma unroll
  for (int si = 0; si < 4; ++si) {
    if (si <= w) {
      short8 bK = *(const short8*)((const char*)&kd[0][0] +
                   (16 * si + (l & 15)) * 80 + (l >> 4) * 16);
      f32x4 acc = (f32x4){0.f, 0.f, 0.f, 0.f};
      acc = __builtin_amdgcn_mfma_f32_16x16x32_bf16(aQ, bK, acc, 0, 0, 0);
      #pragma unroll
      for (int j = 0; j < 4; ++j) {
        bool keep = (si < w) || ((l & 15) <= tl0 + j);
        Aq[16 * w + tl0 + j][16 * si + (l & 15)] = keep ? f2bf(acc[j]) : 0;
      }
    } else {
      #pragma unroll
      for (int j = 0; j < 4; ++j)
        Aq[16 * w + tl0 + j][16 * si + (l & 15)] = 0;
    }
  }
  __syncthreads();

  short8 aA0 = *(const short8*)((const char*)&Aq[0][0] +
                (16 * w + (l & 15)) * 144 + (l >> 4) * 16);
  short8 aA1 = *(const short8*)((const char*)&Aq[0][0] +
                (16 * w + (l & 15)) * 144 + 64 + (l >> 4) * 16);
  const size_t obase = ((size_t)b * Lq + (size_t)chunk * CHK) * 1024 + h * 64;
  #pragma unroll
  for (int ej = 0; ej < 4; ++ej) {
    f32x4 acc = (f32x4){0.f, 0.f, 0.f, 0.f};
    short8 bV0 = *(const short8*)((const char*)&vT[0][0] +
                  (16 * ej + (l & 15)) * 144 + (l >> 4) * 16);
    short8 bV1 = *(const short8*)((const char*)&vT[0][0] +
                  (16 * ej + (l & 15)) * 144 + 64 + (l >> 4) * 16);
    short8 bS = *(const short8*)((const char*)&ST[0][0] +
                  (16 * ej + (l & 15)) * 80 + (l >> 4) * 16);
    acc = __builtin_amdgcn_mfma_f32_16x16x32_bf16(aA0, bV0, acc, 0, 0, 0);
    acc = __builtin_amdgcn_mfma_f32_16x16x32_bf16(aA1, bV1, acc, 0, 0, 0);
    acc = __builtin_amdgcn_mfma_f32_16x16x32_bf16(aQ,  bS,  acc, 0, 0, 0);
    #pragma unroll
    for (int j = 0; j < 4; ++j) {
      int t = 16 * w + tl0 + j;
      int e = 16 * ej + (l & 15);
      o[obase + (size_t)t * 1024 + e] = acc[j];
    }
  }
}

// --------- group norm + gate multiply -> bf16 A-operand ---------
__global__ __launch_bounds__(256)
void gnorm_gate(const float* __restrict__ o, const unsigned short* __restrict__ gate,
                unsigned short* __restrict__ gated)
{
  const int gid = blockIdx.x * 4 + (threadIdx.x >> 6);
  const int e = threadIdx.x & 63;
  const size_t addr = (size_t)gid * 64 + e;
  float val = o[addr];
  float s = val;
  #pragma unroll
  for (int m = 32; m; m >>= 1) s += __shfl_xor(s, m, 64);
  float mean = s * (1.f / 64.f);
  float d = val - mean;
  float s2 = d * d;
  #pragma unroll
  for (int m = 32; m; m >>= 1) s2 += __shfl_xor(s2, m, 64);
  float y = d * rsqrtf(s2 * (1.f / 64.f) + kEps);
  gated[addr] = f2bf(bf2f(gate[addr]) * y);
}

} // namespace

extern "C" void kernel_launch(void* const* d_in, const int* in_sizes, int n_in,
                              void* d_out, int out_size, void* d_ws, size_t ws_size,
                              hipStream_t stream)
{
  (void)in_sizes; (void)n_in; (void)out_size; (void)ws_size;
  const float* x   = (const float*)d_in[0];
  const float* Wq  = (const float*)d_in[1];
  const float* Wk  = (const float*)d_in[2];
  const float* Wg1 = (const float*)d_in[3];
  const float* Wg2 = (const float*)d_in[4];
  const float* Wv  = (const float*)d_in[5];
  const float* Wg  = (const float*)d_in[6];
  const float* bg  = (const float*)d_in[7];
  const float* Wo  = (const float*)d_in[8];

  // workspace: 177.1 MB total
  char* w = (char*)d_ws;
  unsigned short* xh   = (unsigned short*)w; w += (size_t)Mrows * 1024 * 2;
  unsigned short* qkvh = (unsigned short*)w; w += (size_t)Mrows * QKVS * 2;
  float*  lgb = (float*)w;                   w += (size_t)Mrows * 512 * 4;
  float*  t1  = (float*)w;                   w += (size_t)Mrows * 16 * 4;
  float*  Pst = (float*)w;                   w += (size_t)64 * NCHK * 2048 * 4;
  float*  Dd  = (float*)w;                   w += (size_t)64 * NCHK * 32 * 4;
  unsigned short* Wqkvt = (unsigned short*)w; w += (size_t)QKVS * 1024 * 2;
  unsigned short* Wgt   = (unsigned short*)w; w += (size_t)1024 * 1024 * 2;
  unsigned short* Wot   = (unsigned short*)w; w += (size_t)1024 * 1024 * 2;
  unsigned short* gateh  = qkvh;                  // alias over dead qkvh
  unsigned short* gatedh = (unsigned short*)lgb;  // alias over dead lgb

  // dtype conversions (Wqkvt rows: [0,512)=Wq^T, [512,1024)=Wk^T*scale, [1024,2048)=Wv^T)
  cvt_bf16<<<2048, 256, 0, stream>>>(x, xh, Mrows * 1024 / 4);
  cvt_w_t<<<dim3(8, 16),  256, 0, stream>>>(Wq, Wqkvt, 1024, 512, 1.f);
  cvt_w_t<<<dim3(8, 16),  256, 0, stream>>>(Wk, Wqkvt + (size_t)512 * 1024, 1024, 512, kScale);
  cvt_w_t<<<dim3(16, 16), 256, 0, stream>>>(Wv, Wqkvt + (size_t)1024 * 1024, 1024, 1024, 1.f);
  cvt_w_t<<<dim3(16, 16), 256, 0, stream>>>(Wg, Wgt, 1024, 1024, 1.f);
  cvt_w_t<<<dim3(16, 16), 256, 0, stream>>>(Wo, Wot, 1024, 1024, 1.f);
  // fused q|k|v projection (MFMA)
  gemm_bf16<0><<<dim3(16, 128), 256, 0, stream>>>(xh, Wqkvt, nullptr, qkvh, QKVS);
  gemm_g1<<<Mrows / 16, 256, 0, stream>>>(x, Wg1, t1);
  gemm_g2<<<(Mrows * 512) / 256, 256, 0, stream>>>(t1, Wg2, lgb);
  // chunked recurrence (MFMA)
  gla_chunk_state<<<64 * NCHK, 256, 0, stream>>>(qkvh, lgb, Pst, Dd);
  gla_chain<<<64, 256, 0, stream>>>(Pst, Dd);
  gla_chunk_out<<<64 * NCHK, 256, 0, stream>>>(qkvh, lgb, Pst, (float*)d_out);
  // gate path (qkvh now dead -> gateh alias)
  gemm_bf16<2><<<dim3(8, 128), 256, 0, stream>>>(xh, Wgt, bg, gateh, 1024);
  gnorm_gate<<<(Mrows * H_) / 4, 256, 0, stream>>>((const float*)d_out, gateh, gatedh);
  // output projection
  gemm_bf16<3><<<dim3(8, 128), 256, 0, stream>>>(gatedh, Wot, nullptr, d_out, 1024);
}

// Round 7
// 425.432 us; speedup vs baseline: 24.5893x; 1.0610x over previous
//
#include <hip/hip_runtime.h>
#include <cstdint>

namespace {

constexpr int Lq  = 4096;
constexpr int Bq  = 4;
constexpr int H_  = 16;
constexpr int Mrows = Bq * Lq;               // 16384
constexpr int CHK  = 64;
constexpr int NCHK = Lq / CHK;               // 64
constexpr int QKVS = 3072;                   // fused q|k|v|gate row stride
constexpr float kScale = 0.17677669529663687f;  // 32^-0.5
constexpr float kEps   = 1e-5f;

typedef __attribute__((ext_vector_type(8))) short short8;
typedef __attribute__((ext_vector_type(4))) float f32x4;

__device__ __forceinline__ float bf2f(unsigned short u) {
  return __uint_as_float(((unsigned)u) << 16);
}
__device__ __forceinline__ unsigned short f2bf(float f) {
  unsigned u = __float_as_uint(f);
  u += 0x7fffu + ((u >> 16) & 1u);   // RNE
  return (unsigned short)(u >> 16);
}
__device__ __forceinline__ void gload_lds16(const void* g, void* l) {
  __builtin_amdgcn_global_load_lds(
      (const __attribute__((address_space(1))) void*)g,
      (__attribute__((address_space(3))) void*)l, 16, 0, 0);
}

// ---------- x fp32 -> bf16 ----------
__global__ __launch_bounds__(256)
void cvt_bf16(const float* __restrict__ in, unsigned short* __restrict__ out, int n4)
{
  int i = blockIdx.x * 256 + threadIdx.x;
  const int stride = gridDim.x * 256;
  for (; i < n4; i += stride) {
    float4 f = ((const float4*)in)[i];
    ushort4 u = make_ushort4(f2bf(f.x), f2bf(f.y), f2bf(f.z), f2bf(f.w));
    ((ushort4*)out)[i] = u;
  }
}

// ---------- W[K,N] fp32 -> Wt[N,K] bf16 (optionally scaled) ----------
__global__ __launch_bounds__(256)
void cvt_w_t(const float* __restrict__ W, unsigned short* __restrict__ Wt,
             int K, int N, float scale)
{
  __shared__ float T[64][65];
  const int tid = threadIdx.x;
  const int n0 = blockIdx.x * 64, k0 = blockIdx.y * 64;
  #pragma unroll
  for (int it = 0; it < 4; ++it) {
    int kr = (tid >> 4) + it * 16;
    float4 f = *(const float4*)(W + (size_t)(k0 + kr) * N + n0 + (tid & 15) * 4);
    T[kr][(tid & 15) * 4 + 0] = f.x;
    T[kr][(tid & 15) * 4 + 1] = f.y;
    T[kr][(tid & 15) * 4 + 2] = f.z;
    T[kr][(tid & 15) * 4 + 3] = f.w;
  }
  __syncthreads();
  #pragma unroll
  for (int it = 0; it < 4; ++it) {
    int nr = (tid >> 4) + it * 16;
    int c0 = (tid & 15) * 4;
    ushort4 u = make_ushort4(f2bf(T[c0 + 0][nr] * scale), f2bf(T[c0 + 1][nr] * scale),
                             f2bf(T[c0 + 2][nr] * scale), f2bf(T[c0 + 3][nr] * scale));
    *(ushort4*)(Wt + (size_t)(n0 + nr) * K + k0 + c0) = u;
  }
}

// ---------- bf16 MFMA GEMM: C[M,N] = A[M,1024] @ Wt[N,1024]^T ----------
// XCD-aware bijective swizzle (requires nwg % 8 == 0), bn-fastest decode.
// EPI: 2 = fused qkvg (silu(x+bias[col-2048]) for col>=2048), store bf16
//      3 = plain, store fp32
template<int EPI>
__global__ __launch_bounds__(256)
void gemm_bf16(const unsigned short* __restrict__ A,
               const unsigned short* __restrict__ Bt,
               const float* __restrict__ bias,
               void* __restrict__ Cout, int N)
{
  __shared__ unsigned short As[2][128 * 32];
  __shared__ unsigned short Bs[2][128 * 32];
  const int tid = threadIdx.x;
  const int w = tid >> 6, l = tid & 63;
  const int wr = w >> 1, wc = w & 1;

  const int nbx = gridDim.x;
  const int bid = blockIdx.y * nbx + blockIdx.x;
  const int cpx = (nbx * gridDim.y) >> 3;
  const int swz = (bid & 7) * cpx + (bid >> 3);
  const int m0 = (swz / nbx) * 128, n0 = (swz % nbx) * 128;

  const unsigned short* gA[2];
  const unsigned short* gB[2];
  #pragma unroll
  for (int i = 0; i < 2; ++i) {
    int p = (i * 256 + tid) * 16;
    int L = p ^ (((p >> 7) & 3) << 4);
    int r = L >> 6;
    int ke = (L & 63) >> 1;
    gA[i] = A  + (size_t)(m0 + r) * 1024 + ke;
    gB[i] = Bt + (size_t)(n0 + r) * 1024 + ke;
  }
  int pA[4], pB[4];
  #pragma unroll
  for (int f = 0; f < 4; ++f) {
    int rA = wr * 64 + f * 16 + (l & 15);
    int LA = rA * 64 + (l >> 4) * 16;
    pA[f] = LA ^ (((LA >> 7) & 3) << 4);
    int rB = wc * 64 + f * 16 + (l & 15);
    int LB = rB * 64 + (l >> 4) * 16;
    pB[f] = LB ^ (((LB >> 7) & 3) << 4);
  }

  f32x4 acc[4][4];
  #pragma unroll
  for (int i = 0; i < 4; ++i)
    #pragma unroll
    for (int j = 0; j < 4; ++j)
      acc[i][j] = (f32x4){0.f, 0.f, 0.f, 0.f};

  #pragma unroll
  for (int i = 0; i < 2; ++i) {
    gload_lds16(gA[i], &As[0][(i * 256 + w * 64) * 8]);
    gload_lds16(gB[i], &Bs[0][(i * 256 + w * 64) * 8]);
  }
  __syncthreads();

  int buf = 0;
  for (int ks = 0; ks < 32; ++ks) {
    if (ks < 31) {
      const int k0 = (ks + 1) * 32;
      #pragma unroll
      for (int i = 0; i < 2; ++i) {
        gload_lds16(gA[i] + k0, &As[buf ^ 1][(i * 256 + w * 64) * 8]);
        gload_lds16(gB[i] + k0, &Bs[buf ^ 1][(i * 256 + w * 64) * 8]);
      }
    }
    short8 av[4], bv[4];
    #pragma unroll
    for (int f = 0; f < 4; ++f) {
      av[f] = *(const short8*)((const char*)&As[buf][0] + pA[f]);
      bv[f] = *(const short8*)((const char*)&Bs[buf][0] + pB[f]);
    }
    #pragma unroll
    for (int fi = 0; fi < 4; ++fi)
      #pragma unroll
      for (int fj = 0; fj < 4; ++fj)
        acc[fi][fj] = __builtin_amdgcn_mfma_f32_16x16x32_bf16(
            av[fi], bv[fj], acc[fi][fj], 0, 0, 0);
    __syncthreads();
    buf ^= 1;
  }

  const int cr = (l >> 4) * 4;
  const int cc = l & 15;
  #pragma unroll
  for (int fi = 0; fi < 4; ++fi) {
    #pragma unroll
    for (int fj = 0; fj < 4; ++fj) {
      int row = m0 + wr * 64 + fi * 16 + cr;
      int col = n0 + wc * 64 + fj * 16 + cc;
      #pragma unroll
      for (int j = 0; j < 4; ++j) {
        float x = acc[fi][fj][j];
        if (EPI == 2) {
          if (col >= 2048) {           // gate columns: silu(x + bg)
            float z = x + bias[col - 2048];
            x = z / (1.f + expf(-z));
          }
        }
        if (EPI == 3)
          ((float*)Cout)[(size_t)(row + j) * N + col] = x;
        else
          ((unsigned short*)Cout)[(size_t)(row + j) * N + col] = f2bf(x);
      }
    }
  }
}

// ---------------- t1 = x_bf16[M,1024] @ Wg1[1024,16] (fp32 acc) ----------------
__global__ __launch_bounds__(256)
void gemm_g1(const unsigned short* __restrict__ x, const float* __restrict__ W1,
             float* __restrict__ t1)
{
  __shared__ float Xs[16][64];
  __shared__ float Ws[64][16];
  const int tid = threadIdx.x;
  const int m0 = blockIdx.x * 16;
  const int mi = tid >> 4, n = tid & 15;
  float acc = 0.f;
  for (int k0 = 0; k0 < 1024; k0 += 64) {
    ushort4 xv = *(const ushort4*)(x + (size_t)(m0 + (tid >> 4)) * 1024 + k0 + (tid & 15) * 4);
    Xs[tid >> 4][(tid & 15) * 4 + 0] = bf2f(xv.x);
    Xs[tid >> 4][(tid & 15) * 4 + 1] = bf2f(xv.y);
    Xs[tid >> 4][(tid & 15) * 4 + 2] = bf2f(xv.z);
    Xs[tid >> 4][(tid & 15) * 4 + 3] = bf2f(xv.w);
    *(float4*)&Ws[tid >> 2][(tid & 3) * 4] =
        *(const float4*)(W1 + (size_t)(k0 + (tid >> 2)) * 16 + (tid & 3) * 4);
    __syncthreads();
    #pragma unroll
    for (int kk = 0; kk < 64; ++kk)
      acc = fmaf(Xs[mi][kk], Ws[kk][n], acc);
    __syncthreads();
  }
  t1[(size_t)(m0 + mi) * 16 + n] = acc;
}

// --------- lg = log_sigmoid(t1 @ Wg2) / 16,  [M, 512] fp32 ---------
__global__ __launch_bounds__(256)
void gemm_g2(const float* __restrict__ t1, const float* __restrict__ W2,
             float* __restrict__ lg)
{
  const int idx = blockIdx.x * 256 + threadIdx.x;
  const int m = idx >> 9, n = idx & 511;
  float acc = 0.f;
  #pragma unroll
  for (int kk = 0; kk < 16; ++kk)
    acc = fmaf(t1[m * 16 + kk], W2[kk * 512 + n], acc);
  float ls = fminf(acc, 0.f) - log1pf(expf(-fabsf(acc)));
  lg[idx] = ls * 0.0625f;
}

// ============ chunked GLA — MFMA version (fused qkvg input) ============
// qkv[M][3072]: [0,512)=q, [512,1024)=k, [1024,2048)=v, [2048,3072)=gate
__global__ __launch_bounds__(256)
void gla_chunk_state(const unsigned short* __restrict__ qkv, const float* __restrict__ lg,
                     float* __restrict__ P, float* __restrict__ Dd)
{
  __shared__ __align__(16) float Lc[CHK][32];
  __shared__ __align__(16) unsigned short kdT[32][72];
  __shared__ __align__(16) unsigned short vT[64][72];
  const int blk = blockIdx.x;
  const int bh = blk >> 6, chunk = blk & (NCHK - 1);
  const int b = bh >> 4, h = bh & 15;
  const int tid = threadIdx.x;
  const int w = tid >> 6, l = tid & 63;
  const size_t rbase = ((size_t)b * Lq + (size_t)chunk * CHK) * QKVS;
  const size_t rowk = rbase + 512 + h * 32;
  const size_t rowv = rbase + 1024 + h * 64;
  const size_t rowl = ((size_t)b * Lq + (size_t)chunk * CHK) * 512 + h * 32;

  #pragma unroll
  for (int r = 0; r < 2; ++r) {
    int s4 = (tid + 256 * r) * 4;
    int t = s4 >> 5, d0 = s4 & 31;
    *(float4*)&Lc[t][d0] = *(const float4*)(lg + rowl + (size_t)t * 512 + d0);
  }
  __syncthreads();
  if (tid < 32) {
    float s = 0.f;
    for (int t = 0; t < CHK; ++t) { s += Lc[t][tid]; Lc[t][tid] = s; }
  }
  __syncthreads();
  #pragma unroll
  for (int r = 0; r < 2; ++r) {
    int s4 = (tid + 256 * r) * 4;
    int t = s4 >> 5, d0 = s4 & 31;
    ushort4 kv = *(const ushort4*)(qkv + rowk + (size_t)t * QKVS + d0);
    float4 lc = *(const float4*)&Lc[t][d0];
    float4 ls = *(const float4*)&Lc[CHK - 1][d0];
    kdT[d0 + 0][t] = f2bf(bf2f(kv.x) * expf(ls.x - lc.x));
    kdT[d0 + 1][t] = f2bf(bf2f(kv.y) * expf(ls.y - lc.y));
    kdT[d0 + 2][t] = f2bf(bf2f(kv.z) * expf(ls.z - lc.z));
    kdT[d0 + 3][t] = f2bf(bf2f(kv.w) * expf(ls.w - lc.w));
  }
  #pragma unroll
  for (int r = 0; r < 4; ++r) {
    int s4 = (tid + 256 * r) * 4;
    int t = s4 >> 6, e0 = s4 & 63;
    ushort4 vv = *(const ushort4*)(qkv + rowv + (size_t)t * QKVS + e0);
    vT[e0 + 0][t] = vv.x;
    vT[e0 + 1][t] = vv.y;
    vT[e0 + 2][t] = vv.z;
    vT[e0 + 3][t] = vv.w;
  }
  __syncthreads();
  #pragma unroll
  for (int dj = 0; dj < 2; ++dj) {
    f32x4 acc = (f32x4){0.f, 0.f, 0.f, 0.f};
    #pragma unroll
    for (int ks = 0; ks < 2; ++ks) {
      short8 aV = *(const short8*)((const char*)&vT[0][0] +
                    (16 * w + (l & 15)) * 144 + ks * 64 + (l >> 4) * 16);
      short8 bK = *(const short8*)((const char*)&kdT[0][0] +
                    (16 * dj + (l & 15)) * 144 + ks * 64 + (l >> 4) * 16);
      acc = __builtin_amdgcn_mfma_f32_16x16x32_bf16(aV, bK, acc, 0, 0, 0);
    }
    #pragma unroll
    for (int j = 0; j < 4; ++j) {
      int e = 16 * w + (l >> 4) * 4 + j;
      int d = 16 * dj + (l & 15);
      P[(size_t)blk * 2048 + e * 32 + d] = acc[j];
    }
  }
  if (tid < 32) Dd[(size_t)blk * 32 + tid] = expf(Lc[CHK - 1][tid]);
}

__global__ __launch_bounds__(256)
void gla_chain(float* __restrict__ P, const float* __restrict__ Dd)
{
  const int bh = blockIdx.x;
  const int tid = threadIdx.x;
  float4 sA = {0.f, 0.f, 0.f, 0.f}, sB = {0.f, 0.f, 0.f, 0.f};
  const int fA = tid * 4, fB = tid * 4 + 1024;
  const int d0 = fA & 31;
  for (int i = 0; i < NCHK; ++i) {
    const size_t base = ((size_t)bh * NCHK + i) * 2048;
    float4 dd = *(const float4*)(Dd + ((size_t)bh * NCHK + i) * 32 + d0);
    float4 pa = *(const float4*)(P + base + fA);
    float4 pb = *(const float4*)(P + base + fB);
    *(float4*)(P + base + fA) = sA;
    *(float4*)(P + base + fB) = sB;
    sA.x = fmaf(sA.x, dd.x, pa.x); sA.y = fmaf(sA.y, dd.y, pa.y);
    sA.z = fmaf(sA.z, dd.z, pa.z); sA.w = fmaf(sA.w, dd.w, pa.w);
    sB.x = fmaf(sB.x, dd.x, pb.x); sB.y = fmaf(sB.y, dd.y, pb.y);
    sB.z = fmaf(sB.z, dd.z, pb.z); sB.w = fmaf(sB.w, dd.w, pb.w);
  }
}

// chunk_out + fused group-norm + gate multiply -> bf16 gated [M][1024]
__global__ __launch_bounds__(256)
void gla_chunk_out(const unsigned short* __restrict__ qkv, const float* __restrict__ lg,
                   const float* __restrict__ S, unsigned short* __restrict__ gated)
{
  __shared__ __align__(16) float Lc[CHK][32];
  __shared__ __align__(16) unsigned short qb[CHK][40];
  __shared__ __align__(16) unsigned short kd[CHK][40];
  __shared__ __align__(16) unsigned short vT[64][72];
  __shared__ __align__(16) unsigned short ST[64][40];
  __shared__ __align__(16) unsigned short Aq[64][72];
  const int blk = blockIdx.x;
  const int bh = blk >> 6, chunk = blk & (NCHK - 1);
  const int b = bh >> 4, h = bh & 15;
  const int tid = threadIdx.x;
  const int w = tid >> 6, l = tid & 63;
  const size_t rbase = ((size_t)b * Lq + (size_t)chunk * CHK) * QKVS;
  const size_t rowq = rbase + h * 32;
  const size_t rowk = rbase + 512 + h * 32;
  const size_t rowv = rbase + 1024 + h * 64;
  const size_t rowl = ((size_t)b * Lq + (size_t)chunk * CHK) * 512 + h * 32;

  #pragma unroll
  for (int r = 0; r < 2; ++r) {
    int s4 = (tid + 256 * r) * 4;
    int t = s4 >> 5, d0 = s4 & 31;
    *(float4*)&Lc[t][d0] = *(const float4*)(lg + rowl + (size_t)t * 512 + d0);
  }
  __syncthreads();
  if (tid < 32) {
    float s = 0.f;
    for (int t = 0; t < CHK; ++t) { s += Lc[t][tid]; Lc[t][tid] = s; }
  }
  __syncthreads();
  #pragma unroll
  for (int r = 0; r < 2; ++r) {
    int s4 = (tid + 256 * r) * 4;
    int t = s4 >> 5, d0 = s4 & 31;
    ushort4 kv = *(const ushort4*)(qkv + rowk + (size_t)t * QKVS + d0);
    ushort4 qv = *(const ushort4*)(qkv + rowq + (size_t)t * QKVS + d0);
    float4 lc = *(const float4*)&Lc[t][d0];
    ushort4 ko, qo;
    ko.x = f2bf(bf2f(kv.x) * expf(-lc.x)); qo.x = f2bf(bf2f(qv.x) * expf(lc.x));
    ko.y = f2bf(bf2f(kv.y) * expf(-lc.y)); qo.y = f2bf(bf2f(qv.y) * expf(lc.y));
    ko.z = f2bf(bf2f(kv.z) * expf(-lc.z)); qo.z = f2bf(bf2f(qv.z) * expf(lc.z));
    ko.w = f2bf(bf2f(kv.w) * expf(-lc.w)); qo.w = f2bf(bf2f(qv.w) * expf(lc.w));
    *(ushort4*)&kd[t][d0] = ko;
    *(ushort4*)&qb[t][d0] = qo;
  }
  #pragma unroll
  for (int r = 0; r < 4; ++r) {
    int s4 = (tid + 256 * r) * 4;
    int t = s4 >> 6, e0 = s4 & 63;
    ushort4 vv = *(const ushort4*)(qkv + rowv + (size_t)t * QKVS + e0);
    vT[e0 + 0][t] = vv.x;
    vT[e0 + 1][t] = vv.y;
    vT[e0 + 2][t] = vv.z;
    vT[e0 + 3][t] = vv.w;
  }
  #pragma unroll
  for (int r = 0; r < 2; ++r) {
    int s4 = (tid + 256 * r) * 4;
    int e = s4 >> 5, d0 = s4 & 31;
    float4 f = *(const float4*)(S + (size_t)blk * 2048 + s4);
    ushort4 u = make_ushort4(f2bf(f.x), f2bf(f.y), f2bf(f.z), f2bf(f.w));
    *(ushort4*)&ST[e][d0] = u;
  }
  __syncthreads();

  short8 aQ = *(const short8*)((const char*)&qb[0][0] +
               (16 * w + (l & 15)) * 80 + (l >> 4) * 16);
  const int tl0 = (l >> 4) * 4;
  #pragma unroll
  for (int si = 0; si < 4; ++si) {
    if (si <= w) {
      short8 bK = *(const short8*)((const char*)&kd[0][0] +
                   (16 * si + (l & 15)) * 80 + (l >> 4) * 16);
      f32x4 acc = (f32x4){0.f, 0.f, 0.f, 0.f};
      acc = __builtin_amdgcn_mfma_f32_16x16x32_bf16(aQ, bK, acc, 0, 0, 0);
      #pragma unroll
      for (int j = 0; j < 4; ++j) {
        bool keep = (si < w) || ((l & 15) <= tl0 + j);
        Aq[16 * w + tl0 + j][16 * si + (l & 15)] = keep ? f2bf(acc[j]) : 0;
      }
    } else {
      #pragma unroll
      for (int j = 0; j < 4; ++j)
        Aq[16 * w + tl0 + j][16 * si + (l & 15)] = 0;
    }
  }
  __syncthreads();

  short8 aA0 = *(const short8*)((const char*)&Aq[0][0] +
                (16 * w + (l & 15)) * 144 + (l >> 4) * 16);
  short8 aA1 = *(const short8*)((const char*)&Aq[0][0] +
                (16 * w + (l & 15)) * 144 + 64 + (l >> 4) * 16);
  // keep all 4 e-block accumulators for the in-register group norm
  f32x4 accs[4];
  #pragma unroll
  for (int ej = 0; ej < 4; ++ej) {
    f32x4 acc = (f32x4){0.f, 0.f, 0.f, 0.f};
    short8 bV0 = *(const short8*)((const char*)&vT[0][0] +
                  (16 * ej + (l & 15)) * 144 + (l >> 4) * 16);
    short8 bV1 = *(const short8*)((const char*)&vT[0][0] +
                  (16 * ej + (l & 15)) * 144 + 64 + (l >> 4) * 16);
    short8 bS = *(const short8*)((const char*)&ST[0][0] +
                  (16 * ej + (l & 15)) * 80 + (l >> 4) * 16);
    acc = __builtin_amdgcn_mfma_f32_16x16x32_bf16(aA0, bV0, acc, 0, 0, 0);
    acc = __builtin_amdgcn_mfma_f32_16x16x32_bf16(aA1, bV1, acc, 0, 0, 0);
    acc = __builtin_amdgcn_mfma_f32_16x16x32_bf16(aQ,  bS,  acc, 0, 0, 0);
    accs[ej] = acc;
  }

  // group norm over e=0..63: row t lives in the 16 lanes sharing l>>4
  float mean[4], rstd[4];
  #pragma unroll
  for (int j = 0; j < 4; ++j) {
    float s  = accs[0][j] + accs[1][j] + accs[2][j] + accs[3][j];
    float q2 = accs[0][j] * accs[0][j] + accs[1][j] * accs[1][j]
             + accs[2][j] * accs[2][j] + accs[3][j] * accs[3][j];
    #pragma unroll
    for (int m = 1; m <= 8; m <<= 1) {
      s  += __shfl_xor(s, m, 64);
      q2 += __shfl_xor(q2, m, 64);
    }
    float mu = s * (1.f / 64.f);
    mean[j] = mu;
    rstd[j] = rsqrtf(q2 * (1.f / 64.f) - mu * mu + kEps);
  }

  const size_t gbase = rbase + 2048 + h * 64;
  const size_t obase = ((size_t)b * Lq + (size_t)chunk * CHK) * 1024 + h * 64;
  #pragma unroll
  for (int ej = 0; ej < 4; ++ej) {
    int e = 16 * ej + (l & 15);
    #pragma unroll
    for (int j = 0; j < 4; ++j) {
      int t = 16 * w + tl0 + j;
      float gate = bf2f(qkv[gbase + (size_t)t * QKVS + e]);
      float y = (accs[ej][j] - mean[j]) * rstd[j];
      gated[obase + (size_t)t * 1024 + e] = f2bf(gate * y);
    }
  }
}

} // namespace

extern "C" void kernel_launch(void* const* d_in, const int* in_sizes, int n_in,
                              void* d_out, int out_size, void* d_ws, size_t ws_size,
                              hipStream_t stream)
{
  (void)in_sizes; (void)n_in; (void)out_size; (void)ws_size;
  const float* x   = (const float*)d_in[0];
  const float* Wq  = (const float*)d_in[1];
  const float* Wk  = (const float*)d_in[2];
  const float* Wg1 = (const float*)d_in[3];
  const float* Wg2 = (const float*)d_in[4];
  const float* Wv  = (const float*)d_in[5];
  const float* Wg  = (const float*)d_in[6];
  const float* bg  = (const float*)d_in[7];
  const float* Wo  = (const float*)d_in[8];

  // workspace: 211.3 MB total
  char* w = (char*)d_ws;
  unsigned short* xh   = (unsigned short*)w; w += (size_t)Mrows * 1024 * 2;
  unsigned short* qkvg = (unsigned short*)w; w += (size_t)Mrows * QKVS * 2;
  float*  lgb = (float*)w;                   w += (size_t)Mrows * 512 * 4;
  float*  t1  = (float*)w;                   w += (size_t)Mrows * 16 * 4;
  float*  Pst = (float*)w;                   w += (size_t)64 * NCHK * 2048 * 4;
  float*  Dd  = (float*)w;                   w += (size_t)64 * NCHK * 32 * 4;
  unsigned short* Wqkvgt = (unsigned short*)w; w += (size_t)QKVS * 1024 * 2;
  unsigned short* Wot    = (unsigned short*)w; w += (size_t)1024 * 1024 * 2;
  unsigned short* gated  = xh;   // alias: xh dead after proj GEMM + gemm_g1

  // dtype conversions (Wqkvgt rows: [0,512)=Wq^T, [512,1024)=Wk^T*scale,
  //                    [1024,2048)=Wv^T, [2048,3072)=Wg^T)
  cvt_bf16<<<2048, 256, 0, stream>>>(x, xh, Mrows * 1024 / 4);
  cvt_w_t<<<dim3(8, 16),  256, 0, stream>>>(Wq, Wqkvgt, 1024, 512, 1.f);
  cvt_w_t<<<dim3(8, 16),  256, 0, stream>>>(Wk, Wqkvgt + (size_t)512 * 1024, 1024, 512, kScale);
  cvt_w_t<<<dim3(16, 16), 256, 0, stream>>>(Wv, Wqkvgt + (size_t)1024 * 1024, 1024, 1024, 1.f);
  cvt_w_t<<<dim3(16, 16), 256, 0, stream>>>(Wg, Wqkvgt + (size_t)2048 * 1024, 1024, 1024, 1.f);
  cvt_w_t<<<dim3(16, 16), 256, 0, stream>>>(Wo, Wot, 1024, 1024, 1.f);
  // fused q|k|v|gate projection (MFMA, silu epilogue on gate cols)
  gemm_bf16<2><<<dim3(24, 128), 256, 0, stream>>>(xh, Wqkvgt, bg, qkvg, QKVS);
  gemm_g1<<<Mrows / 16, 256, 0, stream>>>(xh, Wg1, t1);
  gemm_g2<<<(Mrows * 512) / 256, 256, 0, stream>>>(t1, Wg2, lgb);
  // chunked recurrence (MFMA) + fused gnorm/gate epilogue
  gla_chunk_state<<<64 * NCHK, 256, 0, stream>>>(qkvg, lgb, Pst, Dd);
  gla_chain<<<64, 256, 0, stream>>>(Pst, Dd);
  gla_chunk_out<<<64 * NCHK, 256, 0, stream>>>(qkvg, lgb, Pst, gated);
  // output projection (fp32 out)
  gemm_bf16<3><<<dim3(8, 128), 256, 0, stream>>>(gated, Wot, nullptr, d_out, 1024);
}

// Round 8
// 408.864 us; speedup vs baseline: 25.5857x; 1.0405x over previous
//
#include <hip/hip_runtime.h>
#include <cstdint>

namespace {

constexpr int Lq  = 4096;
constexpr int Bq  = 4;
constexpr int H_  = 16;
constexpr int Mrows = Bq * Lq;               // 16384
constexpr int CHK  = 64;
constexpr int NCHK = Lq / CHK;               // 64
constexpr int QKVS = 3072;                   // fused q|k|v|gate row stride
constexpr float kScale = 0.17677669529663687f;  // 32^-0.5
constexpr float kEps   = 1e-5f;

typedef __attribute__((ext_vector_type(8))) short short8;
typedef __attribute__((ext_vector_type(4))) float f32x4;

__device__ __forceinline__ float bf2f(unsigned short u) {
  return __uint_as_float(((unsigned)u) << 16);
}
__device__ __forceinline__ unsigned short f2bf(float f) {
  unsigned u = __float_as_uint(f);
  u += 0x7fffu + ((u >> 16) & 1u);   // RNE
  return (unsigned short)(u >> 16);
}
__device__ __forceinline__ void gload_lds16(const void* g, void* l) {
  __builtin_amdgcn_global_load_lds(
      (const __attribute__((address_space(1))) void*)g,
      (__attribute__((address_space(3))) void*)l, 16, 0, 0);
}

// ---------- x fp32 -> bf16 ----------
__global__ __launch_bounds__(256)
void cvt_bf16(const float* __restrict__ in, unsigned short* __restrict__ out, int n4)
{
  int i = blockIdx.x * 256 + threadIdx.x;
  const int stride = gridDim.x * 256;
  for (; i < n4; i += stride) {
    float4 f = ((const float4*)in)[i];
    ushort4 u = make_ushort4(f2bf(f.x), f2bf(f.y), f2bf(f.z), f2bf(f.w));
    ((ushort4*)out)[i] = u;
  }
}

// ---------- W[K,N] fp32 -> Wt[N,K] bf16 (optionally scaled) ----------
__global__ __launch_bounds__(256)
void cvt_w_t(const float* __restrict__ W, unsigned short* __restrict__ Wt,
             int K, int N, float scale)
{
  __shared__ float T[64][65];
  const int tid = threadIdx.x;
  const int n0 = blockIdx.x * 64, k0 = blockIdx.y * 64;
  #pragma unroll
  for (int it = 0; it < 4; ++it) {
    int kr = (tid >> 4) + it * 16;
    float4 f = *(const float4*)(W + (size_t)(k0 + kr) * N + n0 + (tid & 15) * 4);
    T[kr][(tid & 15) * 4 + 0] = f.x;
    T[kr][(tid & 15) * 4 + 1] = f.y;
    T[kr][(tid & 15) * 4 + 2] = f.z;
    T[kr][(tid & 15) * 4 + 3] = f.w;
  }
  __syncthreads();
  #pragma unroll
  for (int it = 0; it < 4; ++it) {
    int nr = (tid >> 4) + it * 16;
    int c0 = (tid & 15) * 4;
    ushort4 u = make_ushort4(f2bf(T[c0 + 0][nr] * scale), f2bf(T[c0 + 1][nr] * scale),
                             f2bf(T[c0 + 2][nr] * scale), f2bf(T[c0 + 3][nr] * scale));
    *(ushort4*)(Wt + (size_t)(n0 + nr) * K + k0 + c0) = u;
  }
}

// ---------- bf16 MFMA GEMM: C[M,N] = A[M,1024] @ Wt[N,1024]^T ----------
// 2-level L2-aware swizzle: XCD owns 16 contiguous M-panels; within XCD,
// order = nsup-outer (8 N-blocks), m-mid, n-fastest. Working set per XCD
// ~= 2MB B-chunk + A-panel < 4MB L2. Requires gridDim.x % 8 == 0 and
// gridDim.y % 8 == 0.
// EPI: 2 = fused qkvg (silu(x+bias[col-2048]) for col>=2048), store bf16
//      3 = plain, store fp32
template<int EPI>
__global__ __launch_bounds__(256)
void gemm_bf16(const unsigned short* __restrict__ A,
               const unsigned short* __restrict__ Bt,
               const float* __restrict__ bias,
               void* __restrict__ Cout, int N)
{
  __shared__ unsigned short As[2][128 * 32];
  __shared__ unsigned short Bs[2][128 * 32];
  const int tid = threadIdx.x;
  const int w = tid >> 6, l = tid & 63;
  const int wr = w >> 1, wc = w & 1;

  const int nbx = gridDim.x;
  const int bid = blockIdx.y * nbx + blockIdx.x;
  const int xcd = bid & 7;
  const int idx = bid >> 3;
  const int mPanels = gridDim.y >> 3;        // M-panels per XCD
  const int perNsup = mPanels * 8;           // blocks per (xcd, nsup)
  const int nsup = idx / perNsup;
  const int rem  = idx - nsup * perNsup;
  const int mi = rem >> 3, ni = rem & 7;
  const int m0 = (xcd * mPanels + mi) * 128;
  const int n0 = (nsup * 8 + ni) * 128;

  const unsigned short* gA[2];
  const unsigned short* gB[2];
  #pragma unroll
  for (int i = 0; i < 2; ++i) {
    int p = (i * 256 + tid) * 16;
    int L = p ^ (((p >> 7) & 3) << 4);
    int r = L >> 6;
    int ke = (L & 63) >> 1;
    gA[i] = A  + (size_t)(m0 + r) * 1024 + ke;
    gB[i] = Bt + (size_t)(n0 + r) * 1024 + ke;
  }
  int pA[4], pB[4];
  #pragma unroll
  for (int f = 0; f < 4; ++f) {
    int rA = wr * 64 + f * 16 + (l & 15);
    int LA = rA * 64 + (l >> 4) * 16;
    pA[f] = LA ^ (((LA >> 7) & 3) << 4);
    int rB = wc * 64 + f * 16 + (l & 15);
    int LB = rB * 64 + (l >> 4) * 16;
    pB[f] = LB ^ (((LB >> 7) & 3) << 4);
  }

  f32x4 acc[4][4];
  #pragma unroll
  for (int i = 0; i < 4; ++i)
    #pragma unroll
    for (int j = 0; j < 4; ++j)
      acc[i][j] = (f32x4){0.f, 0.f, 0.f, 0.f};

  #pragma unroll
  for (int i = 0; i < 2; ++i) {
    gload_lds16(gA[i], &As[0][(i * 256 + w * 64) * 8]);
    gload_lds16(gB[i], &Bs[0][(i * 256 + w * 64) * 8]);
  }
  __syncthreads();

  int buf = 0;
  for (int ks = 0; ks < 32; ++ks) {
    if (ks < 31) {
      const int k0 = (ks + 1) * 32;
      #pragma unroll
      for (int i = 0; i < 2; ++i) {
        gload_lds16(gA[i] + k0, &As[buf ^ 1][(i * 256 + w * 64) * 8]);
        gload_lds16(gB[i] + k0, &Bs[buf ^ 1][(i * 256 + w * 64) * 8]);
      }
    }
    short8 av[4], bv[4];
    #pragma unroll
    for (int f = 0; f < 4; ++f) {
      av[f] = *(const short8*)((const char*)&As[buf][0] + pA[f]);
      bv[f] = *(const short8*)((const char*)&Bs[buf][0] + pB[f]);
    }
    #pragma unroll
    for (int fi = 0; fi < 4; ++fi)
      #pragma unroll
      for (int fj = 0; fj < 4; ++fj)
        acc[fi][fj] = __builtin_amdgcn_mfma_f32_16x16x32_bf16(
            av[fi], bv[fj], acc[fi][fj], 0, 0, 0);
    __syncthreads();
    buf ^= 1;
  }

  const int cr = (l >> 4) * 4;
  const int cc = l & 15;
  #pragma unroll
  for (int fi = 0; fi < 4; ++fi) {
    #pragma unroll
    for (int fj = 0; fj < 4; ++fj) {
      int row = m0 + wr * 64 + fi * 16 + cr;
      int col = n0 + wc * 64 + fj * 16 + cc;
      #pragma unroll
      for (int j = 0; j < 4; ++j) {
        float x = acc[fi][fj][j];
        if (EPI == 2) {
          if (col >= 2048) {           // gate columns: silu(x + bg)
            float z = x + bias[col - 2048];
            x = z / (1.f + expf(-z));
          }
        }
        if (EPI == 3)
          ((float*)Cout)[(size_t)(row + j) * N + col] = x;
        else
          ((unsigned short*)Cout)[(size_t)(row + j) * N + col] = f2bf(x);
      }
    }
  }
}

// ---------------- t1 = x_bf16[M,1024] @ Wg1[1024,16] (fp32 acc) ----------------
__global__ __launch_bounds__(256)
void gemm_g1(const unsigned short* __restrict__ x, const float* __restrict__ W1,
             float* __restrict__ t1)
{
  __shared__ float Xs[16][64];
  __shared__ float Ws[64][16];
  const int tid = threadIdx.x;
  const int m0 = blockIdx.x * 16;
  const int mi = tid >> 4, n = tid & 15;
  float acc = 0.f;
  for (int k0 = 0; k0 < 1024; k0 += 64) {
    ushort4 xv = *(const ushort4*)(x + (size_t)(m0 + (tid >> 4)) * 1024 + k0 + (tid & 15) * 4);
    Xs[tid >> 4][(tid & 15) * 4 + 0] = bf2f(xv.x);
    Xs[tid >> 4][(tid & 15) * 4 + 1] = bf2f(xv.y);
    Xs[tid >> 4][(tid & 15) * 4 + 2] = bf2f(xv.z);
    Xs[tid >> 4][(tid & 15) * 4 + 3] = bf2f(xv.w);
    *(float4*)&Ws[tid >> 2][(tid & 3) * 4] =
        *(const float4*)(W1 + (size_t)(k0 + (tid >> 2)) * 16 + (tid & 3) * 4);
    __syncthreads();
    #pragma unroll
    for (int kk = 0; kk < 64; ++kk)
      acc = fmaf(Xs[mi][kk], Ws[kk][n], acc);
    __syncthreads();
  }
  t1[(size_t)(m0 + mi) * 16 + n] = acc;
}

// --------- lg = log_sigmoid(t1 @ Wg2) / 16,  [M, 512] fp32 ---------
__global__ __launch_bounds__(256)
void gemm_g2(const float* __restrict__ t1, const float* __restrict__ W2,
             float* __restrict__ lg)
{
  const int idx = blockIdx.x * 256 + threadIdx.x;
  const int m = idx >> 9, n = idx & 511;
  float acc = 0.f;
  #pragma unroll
  for (int kk = 0; kk < 16; ++kk)
    acc = fmaf(t1[m * 16 + kk], W2[kk * 512 + n], acc);
  float ls = fminf(acc, 0.f) - log1pf(expf(-fabsf(acc)));
  lg[idx] = ls * 0.0625f;
}

// ============ chunked GLA — MFMA version (fused qkvg input) ============
// qkv[M][3072]: [0,512)=q, [512,1024)=k, [1024,2048)=v, [2048,3072)=gate
__global__ __launch_bounds__(256)
void gla_chunk_state(const unsigned short* __restrict__ qkv, const float* __restrict__ lg,
                     float* __restrict__ P, float* __restrict__ Dd)
{
  __shared__ __align__(16) float Lc[CHK][32];
  __shared__ __align__(16) unsigned short kdT[32][72];
  __shared__ __align__(16) unsigned short vT[64][72];
  const int blk = blockIdx.x;
  const int bh = blk >> 6, chunk = blk & (NCHK - 1);
  const int b = bh >> 4, h = bh & 15;
  const int tid = threadIdx.x;
  const int w = tid >> 6, l = tid & 63;
  const size_t rbase = ((size_t)b * Lq + (size_t)chunk * CHK) * QKVS;
  const size_t rowk = rbase + 512 + h * 32;
  const size_t rowv = rbase + 1024 + h * 64;
  const size_t rowl = ((size_t)b * Lq + (size_t)chunk * CHK) * 512 + h * 32;

  #pragma unroll
  for (int r = 0; r < 2; ++r) {
    int s4 = (tid + 256 * r) * 4;
    int t = s4 >> 5, d0 = s4 & 31;
    *(float4*)&Lc[t][d0] = *(const float4*)(lg + rowl + (size_t)t * 512 + d0);
  }
  __syncthreads();
  if (tid < 32) {
    float s = 0.f;
    for (int t = 0; t < CHK; ++t) { s += Lc[t][tid]; Lc[t][tid] = s; }
  }
  __syncthreads();
  #pragma unroll
  for (int r = 0; r < 2; ++r) {
    int s4 = (tid + 256 * r) * 4;
    int t = s4 >> 5, d0 = s4 & 31;
    ushort4 kv = *(const ushort4*)(qkv + rowk + (size_t)t * QKVS + d0);
    float4 lc = *(const float4*)&Lc[t][d0];
    float4 ls = *(const float4*)&Lc[CHK - 1][d0];
    kdT[d0 + 0][t] = f2bf(bf2f(kv.x) * expf(ls.x - lc.x));
    kdT[d0 + 1][t] = f2bf(bf2f(kv.y) * expf(ls.y - lc.y));
    kdT[d0 + 2][t] = f2bf(bf2f(kv.z) * expf(ls.z - lc.z));
    kdT[d0 + 3][t] = f2bf(bf2f(kv.w) * expf(ls.w - lc.w));
  }
  #pragma unroll
  for (int r = 0; r < 4; ++r) {
    int s4 = (tid + 256 * r) * 4;
    int t = s4 >> 6, e0 = s4 & 63;
    ushort4 vv = *(const ushort4*)(qkv + rowv + (size_t)t * QKVS + e0);
    vT[e0 + 0][t] = vv.x;
    vT[e0 + 1][t] = vv.y;
    vT[e0 + 2][t] = vv.z;
    vT[e0 + 3][t] = vv.w;
  }
  __syncthreads();
  #pragma unroll
  for (int dj = 0; dj < 2; ++dj) {
    f32x4 acc = (f32x4){0.f, 0.f, 0.f, 0.f};
    #pragma unroll
    for (int ks = 0; ks < 2; ++ks) {
      short8 aV = *(const short8*)((const char*)&vT[0][0] +
                    (16 * w + (l & 15)) * 144 + ks * 64 + (l >> 4) * 16);
      short8 bK = *(const short8*)((const char*)&kdT[0][0] +
                    (16 * dj + (l & 15)) * 144 + ks * 64 + (l >> 4) * 16);
      acc = __builtin_amdgcn_mfma_f32_16x16x32_bf16(aV, bK, acc, 0, 0, 0);
    }
    #pragma unroll
    for (int j = 0; j < 4; ++j) {
      int e = 16 * w + (l >> 4) * 4 + j;
      int d = 16 * dj + (l & 15);
      P[(size_t)blk * 2048 + e * 32 + d] = acc[j];
    }
  }
  if (tid < 32) Dd[(size_t)blk * 32 + tid] = expf(Lc[CHK - 1][tid]);
}

__global__ __launch_bounds__(256)
void gla_chain(float* __restrict__ P, const float* __restrict__ Dd)
{
  const int bh = blockIdx.x;
  const int tid = threadIdx.x;
  float4 sA = {0.f, 0.f, 0.f, 0.f}, sB = {0.f, 0.f, 0.f, 0.f};
  const int fA = tid * 4, fB = tid * 4 + 1024;
  const int d0 = fA & 31;
  for (int i = 0; i < NCHK; ++i) {
    const size_t base = ((size_t)bh * NCHK + i) * 2048;
    float4 dd = *(const float4*)(Dd + ((size_t)bh * NCHK + i) * 32 + d0);
    float4 pa = *(const float4*)(P + base + fA);
    float4 pb = *(const float4*)(P + base + fB);
    *(float4*)(P + base + fA) = sA;
    *(float4*)(P + base + fB) = sB;
    sA.x = fmaf(sA.x, dd.x, pa.x); sA.y = fmaf(sA.y, dd.y, pa.y);
    sA.z = fmaf(sA.z, dd.z, pa.z); sA.w = fmaf(sA.w, dd.w, pa.w);
    sB.x = fmaf(sB.x, dd.x, pb.x); sB.y = fmaf(sB.y, dd.y, pb.y);
    sB.z = fmaf(sB.z, dd.z, pb.z); sB.w = fmaf(sB.w, dd.w, pb.w);
  }
}

// chunk_out + fused group-norm + gate multiply -> bf16 gated [M][1024]
__global__ __launch_bounds__(256)
void gla_chunk_out(const unsigned short* __restrict__ qkv, const float* __restrict__ lg,
                   const float* __restrict__ S, unsigned short* __restrict__ gated)
{
  __shared__ __align__(16) float Lc[CHK][32];
  __shared__ __align__(16) unsigned short qb[CHK][40];
  __shared__ __align__(16) unsigned short kd[CHK][40];
  __shared__ __align__(16) unsigned short vT[64][72];
  __shared__ __align__(16) unsigned short ST[64][40];
  __shared__ __align__(16) unsigned short Aq[64][72];
  const int blk = blockIdx.x;
  const int bh = blk >> 6, chunk = blk & (NCHK - 1);
  const int b = bh >> 4, h = bh & 15;
  const int tid = threadIdx.x;
  const int w = tid >> 6, l = tid & 63;
  const size_t rbase = ((size_t)b * Lq + (size_t)chunk * CHK) * QKVS;
  const size_t rowq = rbase + h * 32;
  const size_t rowk = rbase + 512 + h * 32;
  const size_t rowv = rbase + 1024 + h * 64;
  const size_t rowl = ((size_t)b * Lq + (size_t)chunk * CHK) * 512 + h * 32;

  #pragma unroll
  for (int r = 0; r < 2; ++r) {
    int s4 = (tid + 256 * r) * 4;
    int t = s4 >> 5, d0 = s4 & 31;
    *(float4*)&Lc[t][d0] = *(const float4*)(lg + rowl + (size_t)t * 512 + d0);
  }
  __syncthreads();
  if (tid < 32) {
    float s = 0.f;
    for (int t = 0; t < CHK; ++t) { s += Lc[t][tid]; Lc[t][tid] = s; }
  }
  __syncthreads();
  #pragma unroll
  for (int r = 0; r < 2; ++r) {
    int s4 = (tid + 256 * r) * 4;
    int t = s4 >> 5, d0 = s4 & 31;
    ushort4 kv = *(const ushort4*)(qkv + rowk + (size_t)t * QKVS + d0);
    ushort4 qv = *(const ushort4*)(qkv + rowq + (size_t)t * QKVS + d0);
    float4 lc = *(const float4*)&Lc[t][d0];
    ushort4 ko, qo;
    ko.x = f2bf(bf2f(kv.x) * expf(-lc.x)); qo.x = f2bf(bf2f(qv.x) * expf(lc.x));
    ko.y = f2bf(bf2f(kv.y) * expf(-lc.y)); qo.y = f2bf(bf2f(qv.y) * expf(lc.y));
    ko.z = f2bf(bf2f(kv.z) * expf(-lc.z)); qo.z = f2bf(bf2f(qv.z) * expf(lc.z));
    ko.w = f2bf(bf2f(kv.w) * expf(-lc.w)); qo.w = f2bf(bf2f(qv.w) * expf(lc.w));
    *(ushort4*)&kd[t][d0] = ko;
    *(ushort4*)&qb[t][d0] = qo;
  }
  #pragma unroll
  for (int r = 0; r < 4; ++r) {
    int s4 = (tid + 256 * r) * 4;
    int t = s4 >> 6, e0 = s4 & 63;
    ushort4 vv = *(const ushort4*)(qkv + rowv + (size_t)t * QKVS + e0);
    vT[e0 + 0][t] = vv.x;
    vT[e0 + 1][t] = vv.y;
    vT[e0 + 2][t] = vv.z;
    vT[e0 + 3][t] = vv.w;
  }
  #pragma unroll
  for (int r = 0; r < 2; ++r) {
    int s4 = (tid + 256 * r) * 4;
    int e = s4 >> 5, d0 = s4 & 31;
    float4 f = *(const float4*)(S + (size_t)blk * 2048 + s4);
    ushort4 u = make_ushort4(f2bf(f.x), f2bf(f.y), f2bf(f.z), f2bf(f.w));
    *(ushort4*)&ST[e][d0] = u;
  }
  __syncthreads();

  short8 aQ = *(const short8*)((const char*)&qb[0][0] +
               (16 * w + (l & 15)) * 80 + (l >> 4) * 16);
  const int tl0 = (l >> 4) * 4;
  #pragma unroll
  for (int si = 0; si < 4; ++si) {
    if (si <= w) {
      short8 bK = *(const short8*)((const char*)&kd[0][0] +
                   (16 * si + (l & 15)) * 80 + (l >> 4) * 16);
      f32x4 acc = (f32x4){0.f, 0.f, 0.f, 0.f};
      acc = __builtin_amdgcn_mfma_f32_16x16x32_bf16(aQ, bK, acc, 0, 0, 0);
      #pragma unroll
      for (int j = 0; j < 4; ++j) {
        bool keep = (si < w) || ((l & 15) <= tl0 + j);
        Aq[16 * w + tl0 + j][16 * si + (l & 15)] = keep ? f2bf(acc[j]) : 0;
      }
    } else {
      #pragma unroll
      for (int j = 0; j < 4; ++j)
        Aq[16 * w + tl0 + j][16 * si + (l & 15)] = 0;
    }
  }
  __syncthreads();

  short8 aA0 = *(const short8*)((const char*)&Aq[0][0] +
                (16 * w + (l & 15)) * 144 + (l >> 4) * 16);
  short8 aA1 = *(const short8*)((const char*)&Aq[0][0] +
                (16 * w + (l & 15)) * 144 + 64 + (l >> 4) * 16);
  // keep all 4 e-block accumulators for the in-register group norm
  f32x4 accs[4];
  #pragma unroll
  for (int ej = 0; ej < 4; ++ej) {
    f32x4 acc = (f32x4){0.f, 0.f, 0.f, 0.f};
    short8 bV0 = *(const short8*)((const char*)&vT[0][0] +
                  (16 * ej + (l & 15)) * 144 + (l >> 4) * 16);
    short8 bV1 = *(const short8*)((const char*)&vT[0][0] +
                  (16 * ej + (l & 15)) * 144 + 64 + (l >> 4) * 16);
    short8 bS = *(const short8*)((const char*)&ST[0][0] +
                  (16 * ej + (l & 15)) * 80 + (l >> 4) * 16);
    acc = __builtin_amdgcn_mfma_f32_16x16x32_bf16(aA0, bV0, acc, 0, 0, 0);
    acc = __builtin_amdgcn_mfma_f32_16x16x32_bf16(aA1, bV1, acc, 0, 0, 0);
    acc = __builtin_amdgcn_mfma_f32_16x16x32_bf16(aQ,  bS,  acc, 0, 0, 0);
    accs[ej] = acc;
  }

  // group norm over e=0..63: row t lives in the 16 lanes sharing l>>4
  float mean[4], rstd[4];
  #pragma unroll
  for (int j = 0; j < 4; ++j) {
    float s  = accs[0][j] + accs[1][j] + accs[2][j] + accs[3][j];
    float q2 = accs[0][j] * accs[0][j] + accs[1][j] * accs[1][j]
             + accs[2][j] * accs[2][j] + accs[3][j] * accs[3][j];
    #pragma unroll
    for (int m = 1; m <= 8; m <<= 1) {
      s  += __shfl_xor(s, m, 64);
      q2 += __shfl_xor(q2, m, 64);
    }
    float mu = s * (1.f / 64.f);
    mean[j] = mu;
    rstd[j] = rsqrtf(q2 * (1.f / 64.f) - mu * mu + kEps);
  }

  const size_t gbase = rbase + 2048 + h * 64;
  const size_t obase = ((size_t)b * Lq + (size_t)chunk * CHK) * 1024 + h * 64;
  #pragma unroll
  for (int ej = 0; ej < 4; ++ej) {
    int e = 16 * ej + (l & 15);
    #pragma unroll
    for (int j = 0; j < 4; ++j) {
      int t = 16 * w + tl0 + j;
      float gate = bf2f(qkv[gbase + (size_t)t * QKVS + e]);
      float y = (accs[ej][j] - mean[j]) * rstd[j];
      gated[obase + (size_t)t * 1024 + e] = f2bf(gate * y);
    }
  }
}

} // namespace

extern "C" void kernel_launch(void* const* d_in, const int* in_sizes, int n_in,
                              void* d_out, int out_size, void* d_ws, size_t ws_size,
                              hipStream_t stream)
{
  (void)in_sizes; (void)n_in; (void)out_size; (void)ws_size;
  const float* x   = (const float*)d_in[0];
  const float* Wq  = (const float*)d_in[1];
  const float* Wk  = (const float*)d_in[2];
  const float* Wg1 = (const float*)d_in[3];
  const float* Wg2 = (const float*)d_in[4];
  const float* Wv  = (const float*)d_in[5];
  const float* Wg  = (const float*)d_in[6];
  const float* bg  = (const float*)d_in[7];
  const float* Wo  = (const float*)d_in[8];

  // workspace: 211.3 MB total
  char* w = (char*)d_ws;
  unsigned short* xh   = (unsigned short*)w; w += (size_t)Mrows * 1024 * 2;
  unsigned short* qkvg = (unsigned short*)w; w += (size_t)Mrows * QKVS * 2;
  float*  lgb = (float*)w;                   w += (size_t)Mrows * 512 * 4;
  float*  t1  = (float*)w;                   w += (size_t)Mrows * 16 * 4;
  float*  Pst = (float*)w;                   w += (size_t)64 * NCHK * 2048 * 4;
  float*  Dd  = (float*)w;                   w += (size_t)64 * NCHK * 32 * 4;
  unsigned short* Wqkvgt = (unsigned short*)w; w += (size_t)QKVS * 1024 * 2;
  unsigned short* Wot    = (unsigned short*)w; w += (size_t)1024 * 1024 * 2;
  unsigned short* gated  = xh;   // alias: xh dead after proj GEMM + gemm_g1

  // dtype conversions (Wqkvgt rows: [0,512)=Wq^T, [512,1024)=Wk^T*scale,
  //                    [1024,2048)=Wv^T, [2048,3072)=Wg^T)
  cvt_bf16<<<2048, 256, 0, stream>>>(x, xh, Mrows * 1024 / 4);
  cvt_w_t<<<dim3(8, 16),  256, 0, stream>>>(Wq, Wqkvgt, 1024, 512, 1.f);
  cvt_w_t<<<dim3(8, 16),  256, 0, stream>>>(Wk, Wqkvgt + (size_t)512 * 1024, 1024, 512, kScale);
  cvt_w_t<<<dim3(16, 16), 256, 0, stream>>>(Wv, Wqkvgt + (size_t)1024 * 1024, 1024, 1024, 1.f);
  cvt_w_t<<<dim3(16, 16), 256, 0, stream>>>(Wg, Wqkvgt + (size_t)2048 * 1024, 1024, 1024, 1.f);
  cvt_w_t<<<dim3(16, 16), 256, 0, stream>>>(Wo, Wot, 1024, 1024, 1.f);
  // fused q|k|v|gate projection (MFMA, silu epilogue on gate cols)
  gemm_bf16<2><<<dim3(24, 128), 256, 0, stream>>>(xh, Wqkvgt, bg, qkvg, QKVS);
  gemm_g1<<<Mrows / 16, 256, 0, stream>>>(xh, Wg1, t1);
  gemm_g2<<<(Mrows * 512) / 256, 256, 0, stream>>>(t1, Wg2, lgb);
  // chunked recurrence (MFMA) + fused gnorm/gate epilogue
  gla_chunk_state<<<64 * NCHK, 256, 0, stream>>>(qkvg, lgb, Pst, Dd);
  gla_chain<<<64, 256, 0, stream>>>(Pst, Dd);
  gla_chunk_out<<<64 * NCHK, 256, 0, stream>>>(qkvg, lgb, Pst, gated);
  // output projection (fp32 out)
  gemm_bf16<3><<<dim3(8, 128), 256, 0, stream>>>(gated, Wot, nullptr, d_out, 1024);
}

// Round 9
// 368.836 us; speedup vs baseline: 28.3624x; 1.1085x over previous
//
#include <hip/hip_runtime.h>
#include <cstdint>

namespace {

constexpr int Lq  = 4096;
constexpr int Bq  = 4;
constexpr int H_  = 16;
constexpr int Mrows = Bq * Lq;               // 16384
constexpr int CHK  = 64;
constexpr int NCHK = Lq / CHK;               // 64
constexpr int QKVS = 3072;                   // fused q|k|v|gate row stride
constexpr float kScale = 0.17677669529663687f;  // 32^-0.5
constexpr float kEps   = 1e-5f;

typedef __attribute__((ext_vector_type(8))) short short8;
typedef __attribute__((ext_vector_type(4))) float f32x4;

__device__ __forceinline__ float bf2f(unsigned short u) {
  return __uint_as_float(((unsigned)u) << 16);
}
__device__ __forceinline__ unsigned short f2bf(float f) {
  unsigned u = __float_as_uint(f);
  u += 0x7fffu + ((u >> 16) & 1u);   // RNE
  return (unsigned short)(u >> 16);
}
__device__ __forceinline__ void gload_lds16(const void* g, void* l) {
  __builtin_amdgcn_global_load_lds(
      (const __attribute__((address_space(1))) void*)g,
      (__attribute__((address_space(3))) void*)l, 16, 0, 0);
}

// ---------- x fp32 -> bf16 ----------
__global__ __launch_bounds__(256)
void cvt_bf16(const float* __restrict__ in, unsigned short* __restrict__ out, int n4)
{
  int i = blockIdx.x * 256 + threadIdx.x;
  const int stride = gridDim.x * 256;
  for (; i < n4; i += stride) {
    float4 f = ((const float4*)in)[i];
    ushort4 u = make_ushort4(f2bf(f.x), f2bf(f.y), f2bf(f.z), f2bf(f.w));
    ((ushort4*)out)[i] = u;
  }
}

// ---------- W[K,N] fp32 -> Wt[N,K] bf16 (optionally scaled) ----------
__global__ __launch_bounds__(256)
void cvt_w_t(const float* __restrict__ W, unsigned short* __restrict__ Wt,
             int K, int N, float scale)
{
  __shared__ float T[64][65];
  const int tid = threadIdx.x;
  const int n0 = blockIdx.x * 64, k0 = blockIdx.y * 64;
  #pragma unroll
  for (int it = 0; it < 4; ++it) {
    int kr = (tid >> 4) + it * 16;
    float4 f = *(const float4*)(W + (size_t)(k0 + kr) * N + n0 + (tid & 15) * 4);
    T[kr][(tid & 15) * 4 + 0] = f.x;
    T[kr][(tid & 15) * 4 + 1] = f.y;
    T[kr][(tid & 15) * 4 + 2] = f.z;
    T[kr][(tid & 15) * 4 + 3] = f.w;
  }
  __syncthreads();
  #pragma unroll
  for (int it = 0; it < 4; ++it) {
    int nr = (tid >> 4) + it * 16;
    int c0 = (tid & 15) * 4;
    ushort4 u = make_ushort4(f2bf(T[c0 + 0][nr] * scale), f2bf(T[c0 + 1][nr] * scale),
                             f2bf(T[c0 + 2][nr] * scale), f2bf(T[c0 + 3][nr] * scale));
    *(ushort4*)(Wt + (size_t)(n0 + nr) * K + k0 + c0) = u;
  }
}

// ========== 256x256 8-wave phase-split bf16 GEMM, K=1024 ==========
// C[M,N] = A[M,1024] @ Bt[N,1024]^T. 512 threads (8 waves, 2M x 4N).
// LDS: 2 x (A[256][64] + B[256][64]) bf16 = 128 KB, double-buffered.
// Staging: linear LDS dest via global_load_lds(16B) + inverse-swizzled
// global source; reads apply the same involution (2 lanes/bank).
// Schedule: per K-tile 4 quadrant-phases; counted vmcnt(2) once per tile;
// raw s_barrier + sched_barrier(0); setprio around MFMA cluster.
// EPI: 2 = silu(x+bias[col-2048]) for col>=2048, store bf16
//      3 = plain, store fp32
template<int EPI>
__global__ __launch_bounds__(512, 1)
void gemm256(const unsigned short* __restrict__ A,
             const unsigned short* __restrict__ Bt,
             const float* __restrict__ bias,
             void* __restrict__ Cout, int N)
{
  __shared__ __align__(16) unsigned short As[2][256 * 64];
  __shared__ __align__(16) unsigned short Bs[2][256 * 64];
  const int tid = threadIdx.x;
  const int w = tid >> 6, l = tid & 63;
  const int wm = w >> 2, wn = w & 3;

  // 2-level XCD-aware swizzle (bijective; 8 M-panels/XCD fixed, ni-pairs)
  const int nbx = gridDim.x;
  const int bid = blockIdx.y * nbx + blockIdx.x;
  const int xcd = bid & 7;
  const int idx = bid >> 3;
  const int nsup = idx >> 4;           // 16 = 8 mPanels * 2 ni
  const int rem = idx & 15;
  const int mi = rem >> 1, ni = rem & 1;
  const int m0 = (xcd * 8 + mi) * 256;
  const int n0 = (nsup * 2 + ni) * 256;

  // staging source: physical byte p = i*8192 + tid*16 holds logical
  // (row = i*64 + tid>>3, elem8 = (tid&7)^((tid>>3)&7))
  const int srow = tid >> 3;
  const int scol = ((tid & 7) ^ ((tid >> 3) & 7)) * 8;
  const unsigned short* gAp[4];
  const unsigned short* gBp[4];
  #pragma unroll
  for (int i = 0; i < 4; ++i) {
    gAp[i] = A  + (size_t)(m0 + i * 64 + srow) * 1024 + scol;
    gBp[i] = Bt + (size_t)(n0 + i * 64 + srow) * 1024 + scol;
  }

  // read-side swizzle constants
  const int rbA = wm * 128 + (l & 15);
  const int rbB = wn * 64 + (l & 15);
  const int swzA = (rbA & 7) << 4;
  const int swzB = (rbB & 7) << 4;
  const int colb = (l >> 4) * 16;

  f32x4 acc[8][4];
  #pragma unroll
  for (int i = 0; i < 8; ++i)
    #pragma unroll
    for (int j = 0; j < 4; ++j)
      acc[i][j] = (f32x4){0.f, 0.f, 0.f, 0.f};

  // prologue: stage tile 0 into buf 0
  #pragma unroll
  for (int i = 0; i < 4; ++i) {
    gload_lds16(gAp[i], (char*)&As[0][0] + i * 8192 + w * 1024);
    gload_lds16(gBp[i], (char*)&Bs[0][0] + i * 8192 + w * 1024);
    gAp[i] += 64; gBp[i] += 64;
  }

  int cur = 0;
  for (int t = 0; t < 16; ++t) {
    char* ldsA  = (char*)&As[cur][0];
    char* ldsB  = (char*)&Bs[cur][0];
    char* ldsAn = (char*)&As[cur ^ 1][0];
    char* ldsBn = (char*)&Bs[cur ^ 1][0];

    // phase-0 preamble: issue half-tile 0 of tile t+1, then wait for tile t
    if (t < 15) {
      gload_lds16(gAp[0], ldsAn + w * 1024);
      gload_lds16(gBp[0], ldsBn + w * 1024);
      gAp[0] += 64; gBp[0] += 64;
      asm volatile("s_waitcnt vmcnt(2)" ::: "memory");
    } else {
      asm volatile("s_waitcnt vmcnt(0)" ::: "memory");
    }
    __builtin_amdgcn_s_barrier();
    __builtin_amdgcn_sched_barrier(0);

    #pragma unroll
    for (int q = 0; q < 4; ++q) {
      const int mh = q >> 1, nh = q & 1;
      short8 av[4][2], bv[2][2];
      #pragma unroll
      for (int mf = 0; mf < 4; ++mf) {
        int row = rbA + (mh * 4 + mf) * 16;
        #pragma unroll
        for (int ks = 0; ks < 2; ++ks)
          av[mf][ks] = *(const short8*)(ldsA + row * 128 + ((ks * 64 + colb) ^ swzA));
      }
      #pragma unroll
      for (int nf = 0; nf < 2; ++nf) {
        int row = rbB + (nh * 2 + nf) * 16;
        #pragma unroll
        for (int ks = 0; ks < 2; ++ks)
          bv[nf][ks] = *(const short8*)(ldsB + row * 128 + ((ks * 64 + colb) ^ swzB));
      }
      if (q > 0) {
        if (t < 15) {
          gload_lds16(gAp[q], ldsAn + q * 8192 + w * 1024);
          gload_lds16(gBp[q], ldsBn + q * 8192 + w * 1024);
          gAp[q] += 64; gBp[q] += 64;
        }
        __builtin_amdgcn_s_barrier();
      }
      asm volatile("s_waitcnt lgkmcnt(0)" ::: "memory");
      __builtin_amdgcn_sched_barrier(0);
      __builtin_amdgcn_s_setprio(1);
      #pragma unroll
      for (int ks = 0; ks < 2; ++ks)
        #pragma unroll
        for (int mf = 0; mf < 4; ++mf)
          #pragma unroll
          for (int nf = 0; nf < 2; ++nf)
            acc[mh * 4 + mf][nh * 2 + nf] = __builtin_amdgcn_mfma_f32_16x16x32_bf16(
                av[mf][ks], bv[nf][ks], acc[mh * 4 + mf][nh * 2 + nf], 0, 0, 0);
      __builtin_amdgcn_s_setprio(0);
      __builtin_amdgcn_s_barrier();
      __builtin_amdgcn_sched_barrier(0);
    }
    cur ^= 1;
  }

  // epilogue
  const int cr = (l >> 4) * 4;
  const int cc = l & 15;
  #pragma unroll
  for (int mf = 0; mf < 8; ++mf) {
    #pragma unroll
    for (int nf = 0; nf < 4; ++nf) {
      int row = m0 + wm * 128 + mf * 16 + cr;
      int col = n0 + wn * 64 + nf * 16 + cc;
      #pragma unroll
      for (int j = 0; j < 4; ++j) {
        float x = acc[mf][nf][j];
        if (EPI == 2) {
          if (col >= 2048) {
            float z = x + bias[col - 2048];
            x = z / (1.f + expf(-z));
          }
        }
        if (EPI == 3)
          ((float*)Cout)[(size_t)(row + j) * N + col] = x;
        else
          ((unsigned short*)Cout)[(size_t)(row + j) * N + col] = f2bf(x);
      }
    }
  }
}

// ---------------- t1 = x_bf16[M,1024] @ Wg1[1024,16] (fp32 acc) ----------------
__global__ __launch_bounds__(256)
void gemm_g1(const unsigned short* __restrict__ x, const float* __restrict__ W1,
             float* __restrict__ t1)
{
  __shared__ float Xs[16][64];
  __shared__ float Ws[64][16];
  const int tid = threadIdx.x;
  const int m0 = blockIdx.x * 16;
  const int mi = tid >> 4, n = tid & 15;
  float acc = 0.f;
  for (int k0 = 0; k0 < 1024; k0 += 64) {
    ushort4 xv = *(const ushort4*)(x + (size_t)(m0 + (tid >> 4)) * 1024 + k0 + (tid & 15) * 4);
    Xs[tid >> 4][(tid & 15) * 4 + 0] = bf2f(xv.x);
    Xs[tid >> 4][(tid & 15) * 4 + 1] = bf2f(xv.y);
    Xs[tid >> 4][(tid & 15) * 4 + 2] = bf2f(xv.z);
    Xs[tid >> 4][(tid & 15) * 4 + 3] = bf2f(xv.w);
    *(float4*)&Ws[tid >> 2][(tid & 3) * 4] =
        *(const float4*)(W1 + (size_t)(k0 + (tid >> 2)) * 16 + (tid & 3) * 4);
    __syncthreads();
    #pragma unroll
    for (int kk = 0; kk < 64; ++kk)
      acc = fmaf(Xs[mi][kk], Ws[kk][n], acc);
    __syncthreads();
  }
  t1[(size_t)(m0 + mi) * 16 + n] = acc;
}

// --------- lg = log_sigmoid(t1 @ Wg2) / 16,  [M, 512] fp32 ---------
__global__ __launch_bounds__(256)
void gemm_g2(const float* __restrict__ t1, const float* __restrict__ W2,
             float* __restrict__ lg)
{
  const int idx = blockIdx.x * 256 + threadIdx.x;
  const int m = idx >> 9, n = idx & 511;
  float acc = 0.f;
  #pragma unroll
  for (int kk = 0; kk < 16; ++kk)
    acc = fmaf(t1[m * 16 + kk], W2[kk * 512 + n], acc);
  float ls = fminf(acc, 0.f) - log1pf(expf(-fabsf(acc)));
  lg[idx] = ls * 0.0625f;
}

// ============ chunked GLA — MFMA version (fused qkvg input) ============
// qkv[M][3072]: [0,512)=q, [512,1024)=k, [1024,2048)=v, [2048,3072)=gate
__global__ __launch_bounds__(256)
void gla_chunk_state(const unsigned short* __restrict__ qkv, const float* __restrict__ lg,
                     float* __restrict__ P, float* __restrict__ Dd)
{
  __shared__ __align__(16) float Lc[CHK][32];
  __shared__ __align__(16) unsigned short kdT[32][72];
  __shared__ __align__(16) unsigned short vT[64][72];
  const int blk = blockIdx.x;
  const int bh = blk >> 6, chunk = blk & (NCHK - 1);
  const int b = bh >> 4, h = bh & 15;
  const int tid = threadIdx.x;
  const int w = tid >> 6, l = tid & 63;
  const size_t rbase = ((size_t)b * Lq + (size_t)chunk * CHK) * QKVS;
  const size_t rowk = rbase + 512 + h * 32;
  const size_t rowv = rbase + 1024 + h * 64;
  const size_t rowl = ((size_t)b * Lq + (size_t)chunk * CHK) * 512 + h * 32;

  #pragma unroll
  for (int r = 0; r < 2; ++r) {
    int s4 = (tid + 256 * r) * 4;
    int t = s4 >> 5, d0 = s4 & 31;
    *(float4*)&Lc[t][d0] = *(const float4*)(lg + rowl + (size_t)t * 512 + d0);
  }
  __syncthreads();
  if (tid < 32) {
    float s = 0.f;
    for (int t = 0; t < CHK; ++t) { s += Lc[t][tid]; Lc[t][tid] = s; }
  }
  __syncthreads();
  #pragma unroll
  for (int r = 0; r < 2; ++r) {
    int s4 = (tid + 256 * r) * 4;
    int t = s4 >> 5, d0 = s4 & 31;
    ushort4 kv = *(const ushort4*)(qkv + rowk + (size_t)t * QKVS + d0);
    float4 lc = *(const float4*)&Lc[t][d0];
    float4 ls = *(const float4*)&Lc[CHK - 1][d0];
    kdT[d0 + 0][t] = f2bf(bf2f(kv.x) * expf(ls.x - lc.x));
    kdT[d0 + 1][t] = f2bf(bf2f(kv.y) * expf(ls.y - lc.y));
    kdT[d0 + 2][t] = f2bf(bf2f(kv.z) * expf(ls.z - lc.z));
    kdT[d0 + 3][t] = f2bf(bf2f(kv.w) * expf(ls.w - lc.w));
  }
  #pragma unroll
  for (int r = 0; r < 4; ++r) {
    int s4 = (tid + 256 * r) * 4;
    int t = s4 >> 6, e0 = s4 & 63;
    ushort4 vv = *(const ushort4*)(qkv + rowv + (size_t)t * QKVS + e0);
    vT[e0 + 0][t] = vv.x;
    vT[e0 + 1][t] = vv.y;
    vT[e0 + 2][t] = vv.z;
    vT[e0 + 3][t] = vv.w;
  }
  __syncthreads();
  #pragma unroll
  for (int dj = 0; dj < 2; ++dj) {
    f32x4 acc = (f32x4){0.f, 0.f, 0.f, 0.f};
    #pragma unroll
    for (int ks = 0; ks < 2; ++ks) {
      short8 aV = *(const short8*)((const char*)&vT[0][0] +
                    (16 * w + (l & 15)) * 144 + ks * 64 + (l >> 4) * 16);
      short8 bK = *(const short8*)((const char*)&kdT[0][0] +
                    (16 * dj + (l & 15)) * 144 + ks * 64 + (l >> 4) * 16);
      acc = __builtin_amdgcn_mfma_f32_16x16x32_bf16(aV, bK, acc, 0, 0, 0);
    }
    #pragma unroll
    for (int j = 0; j < 4; ++j) {
      int e = 16 * w + (l >> 4) * 4 + j;
      int d = 16 * dj + (l & 15);
      P[(size_t)blk * 2048 + e * 32 + d] = acc[j];
    }
  }
  if (tid < 32) Dd[(size_t)blk * 32 + tid] = expf(Lc[CHK - 1][tid]);
}

__global__ __launch_bounds__(256)
void gla_chain(float* __restrict__ P, const float* __restrict__ Dd)
{
  const int bh = blockIdx.x;
  const int tid = threadIdx.x;
  float4 sA = {0.f, 0.f, 0.f, 0.f}, sB = {0.f, 0.f, 0.f, 0.f};
  const int fA = tid * 4, fB = tid * 4 + 1024;
  const int d0 = fA & 31;
  for (int i = 0; i < NCHK; ++i) {
    const size_t base = ((size_t)bh * NCHK + i) * 2048;
    float4 dd = *(const float4*)(Dd + ((size_t)bh * NCHK + i) * 32 + d0);
    float4 pa = *(const float4*)(P + base + fA);
    float4 pb = *(const float4*)(P + base + fB);
    *(float4*)(P + base + fA) = sA;
    *(float4*)(P + base + fB) = sB;
    sA.x = fmaf(sA.x, dd.x, pa.x); sA.y = fmaf(sA.y, dd.y, pa.y);
    sA.z = fmaf(sA.z, dd.z, pa.z); sA.w = fmaf(sA.w, dd.w, pa.w);
    sB.x = fmaf(sB.x, dd.x, pb.x); sB.y = fmaf(sB.y, dd.y, pb.y);
    sB.z = fmaf(sB.z, dd.z, pb.z); sB.w = fmaf(sB.w, dd.w, pb.w);
  }
}

// chunk_out + fused group-norm + gate multiply -> bf16 gated [M][1024]
__global__ __launch_bounds__(256)
void gla_chunk_out(const unsigned short* __restrict__ qkv, const float* __restrict__ lg,
                   const float* __restrict__ S, unsigned short* __restrict__ gated)
{
  __shared__ __align__(16) float Lc[CHK][32];
  __shared__ __align__(16) unsigned short qb[CHK][40];
  __shared__ __align__(16) unsigned short kd[CHK][40];
  __shared__ __align__(16) unsigned short vT[64][72];
  __shared__ __align__(16) unsigned short ST[64][40];
  __shared__ __align__(16) unsigned short Aq[64][72];
  const int blk = blockIdx.x;
  const int bh = blk >> 6, chunk = blk & (NCHK - 1);
  const int b = bh >> 4, h = bh & 15;
  const int tid = threadIdx.x;
  const int w = tid >> 6, l = tid & 63;
  const size_t rbase = ((size_t)b * Lq + (size_t)chunk * CHK) * QKVS;
  const size_t rowq = rbase + h * 32;
  const size_t rowk = rbase + 512 + h * 32;
  const size_t rowv = rbase + 1024 + h * 64;
  const size_t rowl = ((size_t)b * Lq + (size_t)chunk * CHK) * 512 + h * 32;

  #pragma unroll
  for (int r = 0; r < 2; ++r) {
    int s4 = (tid + 256 * r) * 4;
    int t = s4 >> 5, d0 = s4 & 31;
    *(float4*)&Lc[t][d0] = *(const float4*)(lg + rowl + (size_t)t * 512 + d0);
  }
  __syncthreads();
  if (tid < 32) {
    float s = 0.f;
    for (int t = 0; t < CHK; ++t) { s += Lc[t][tid]; Lc[t][tid] = s; }
  }
  __syncthreads();
  #pragma unroll
  for (int r = 0; r < 2; ++r) {
    int s4 = (tid + 256 * r) * 4;
    int t = s4 >> 5, d0 = s4 & 31;
    ushort4 kv = *(const ushort4*)(qkv + rowk + (size_t)t * QKVS + d0);
    ushort4 qv = *(const ushort4*)(qkv + rowq + (size_t)t * QKVS + d0);
    float4 lc = *(const float4*)&Lc[t][d0];
    ushort4 ko, qo;
    ko.x = f2bf(bf2f(kv.x) * expf(-lc.x)); qo.x = f2bf(bf2f(qv.x) * expf(lc.x));
    ko.y = f2bf(bf2f(kv.y) * expf(-lc.y)); qo.y = f2bf(bf2f(qv.y) * expf(lc.y));
    ko.z = f2bf(bf2f(kv.z) * expf(-lc.z)); qo.z = f2bf(bf2f(qv.z) * expf(lc.z));
    ko.w = f2bf(bf2f(kv.w) * expf(-lc.w)); qo.w = f2bf(bf2f(qv.w) * expf(lc.w));
    *(ushort4*)&kd[t][d0] = ko;
    *(ushort4*)&qb[t][d0] = qo;
  }
  #pragma unroll
  for (int r = 0; r < 4; ++r) {
    int s4 = (tid + 256 * r) * 4;
    int t = s4 >> 6, e0 = s4 & 63;
    ushort4 vv = *(const ushort4*)(qkv + rowv + (size_t)t * QKVS + e0);
    vT[e0 + 0][t] = vv.x;
    vT[e0 + 1][t] = vv.y;
    vT[e0 + 2][t] = vv.z;
    vT[e0 + 3][t] = vv.w;
  }
  #pragma unroll
  for (int r = 0; r < 2; ++r) {
    int s4 = (tid + 256 * r) * 4;
    int e = s4 >> 5, d0 = s4 & 31;
    float4 f = *(const float4*)(S + (size_t)blk * 2048 + s4);
    ushort4 u = make_ushort4(f2bf(f.x), f2bf(f.y), f2bf(f.z), f2bf(f.w));
    *(ushort4*)&ST[e][d0] = u;
  }
  __syncthreads();

  short8 aQ = *(const short8*)((const char*)&qb[0][0] +
               (16 * w + (l & 15)) * 80 + (l >> 4) * 16);
  const int tl0 = (l >> 4) * 4;
  #pragma unroll
  for (int si = 0; si < 4; ++si) {
    if (si <= w) {
      short8 bK = *(const short8*)((const char*)&kd[0][0] +
                   (16 * si + (l & 15)) * 80 + (l >> 4) * 16);
      f32x4 acc = (f32x4){0.f, 0.f, 0.f, 0.f};
      acc = __builtin_amdgcn_mfma_f32_16x16x32_bf16(aQ, bK, acc, 0, 0, 0);
      #pragma unroll
      for (int j = 0; j < 4; ++j) {
        bool keep = (si < w) || ((l & 15) <= tl0 + j);
        Aq[16 * w + tl0 + j][16 * si + (l & 15)] = keep ? f2bf(acc[j]) : 0;
      }
    } else {
      #pragma unroll
      for (int j = 0; j < 4; ++j)
        Aq[16 * w + tl0 + j][16 * si + (l & 15)] = 0;
    }
  }
  __syncthreads();

  short8 aA0 = *(const short8*)((const char*)&Aq[0][0] +
                (16 * w + (l & 15)) * 144 + (l >> 4) * 16);
  short8 aA1 = *(const short8*)((const char*)&Aq[0][0] +
                (16 * w + (l & 15)) * 144 + 64 + (l >> 4) * 16);
  f32x4 accs[4];
  #pragma unroll
  for (int ej = 0; ej < 4; ++ej) {
    f32x4 acc = (f32x4){0.f, 0.f, 0.f, 0.f};
    short8 bV0 = *(const short8*)((const char*)&vT[0][0] +
                  (16 * ej + (l & 15)) * 144 + (l >> 4) * 16);
    short8 bV1 = *(const short8*)((const char*)&vT[0][0] +
                  (16 * ej + (l & 15)) * 144 + 64 + (l >> 4) * 16);
    short8 bS = *(const short8*)((const char*)&ST[0][0] +
                  (16 * ej + (l & 15)) * 80 + (l >> 4) * 16);
    acc = __builtin_amdgcn_mfma_f32_16x16x32_bf16(aA0, bV0, acc, 0, 0, 0);
    acc = __builtin_amdgcn_mfma_f32_16x16x32_bf16(aA1, bV1, acc, 0, 0, 0);
    acc = __builtin_amdgcn_mfma_f32_16x16x32_bf16(aQ,  bS,  acc, 0, 0, 0);
    accs[ej] = acc;
  }

  float mean[4], rstd[4];
  #pragma unroll
  for (int j = 0; j < 4; ++j) {
    float s  = accs[0][j] + accs[1][j] + accs[2][j] + accs[3][j];
    float q2 = accs[0][j] * accs[0][j] + accs[1][j] * accs[1][j]
             + accs[2][j] * accs[2][j] + accs[3][j] * accs[3][j];
    #pragma unroll
    for (int m = 1; m <= 8; m <<= 1) {
      s  += __shfl_xor(s, m, 64);
      q2 += __shfl_xor(q2, m, 64);
    }
    float mu = s * (1.f / 64.f);
    mean[j] = mu;
    rstd[j] = rsqrtf(q2 * (1.f / 64.f) - mu * mu + kEps);
  }

  const size_t gbase = rbase + 2048 + h * 64;
  const size_t obase = ((size_t)b * Lq + (size_t)chunk * CHK) * 1024 + h * 64;
  #pragma unroll
  for (int ej = 0; ej < 4; ++ej) {
    int e = 16 * ej + (l & 15);
    #pragma unroll
    for (int j = 0; j < 4; ++j) {
      int t = 16 * w + tl0 + j;
      float gate = bf2f(qkv[gbase + (size_t)t * QKVS + e]);
      float y = (accs[ej][j] - mean[j]) * rstd[j];
      gated[obase + (size_t)t * 1024 + e] = f2bf(gate * y);
    }
  }
}

} // namespace

extern "C" void kernel_launch(void* const* d_in, const int* in_sizes, int n_in,
                              void* d_out, int out_size, void* d_ws, size_t ws_size,
                              hipStream_t stream)
{
  (void)in_sizes; (void)n_in; (void)out_size; (void)ws_size;
  const float* x   = (const float*)d_in[0];
  const float* Wq  = (const float*)d_in[1];
  const float* Wk  = (const float*)d_in[2];
  const float* Wg1 = (const float*)d_in[3];
  const float* Wg2 = (const float*)d_in[4];
  const float* Wv  = (const float*)d_in[5];
  const float* Wg  = (const float*)d_in[6];
  const float* bg  = (const float*)d_in[7];
  const float* Wo  = (const float*)d_in[8];

  // workspace: 211.3 MB total
  char* w = (char*)d_ws;
  unsigned short* xh   = (unsigned short*)w; w += (size_t)Mrows * 1024 * 2;
  unsigned short* qkvg = (unsigned short*)w; w += (size_t)Mrows * QKVS * 2;
  float*  lgb = (float*)w;                   w += (size_t)Mrows * 512 * 4;
  float*  t1  = (float*)w;                   w += (size_t)Mrows * 16 * 4;
  float*  Pst = (float*)w;                   w += (size_t)64 * NCHK * 2048 * 4;
  float*  Dd  = (float*)w;                   w += (size_t)64 * NCHK * 32 * 4;
  unsigned short* Wqkvgt = (unsigned short*)w; w += (size_t)QKVS * 1024 * 2;
  unsigned short* Wot    = (unsigned short*)w; w += (size_t)1024 * 1024 * 2;
  unsigned short* gated  = xh;   // alias: xh dead after proj GEMM + gemm_g1

  // dtype conversions (Wqkvgt rows: [0,512)=Wq^T, [512,1024)=Wk^T*scale,
  //                    [1024,2048)=Wv^T, [2048,3072)=Wg^T)
  cvt_bf16<<<2048, 256, 0, stream>>>(x, xh, Mrows * 1024 / 4);
  cvt_w_t<<<dim3(8, 16),  256, 0, stream>>>(Wq, Wqkvgt, 1024, 512, 1.f);
  cvt_w_t<<<dim3(8, 16),  256, 0, stream>>>(Wk, Wqkvgt + (size_t)512 * 1024, 1024, 512, kScale);
  cvt_w_t<<<dim3(16, 16), 256, 0, stream>>>(Wv, Wqkvgt + (size_t)1024 * 1024, 1024, 1024, 1.f);
  cvt_w_t<<<dim3(16, 16), 256, 0, stream>>>(Wg, Wqkvgt + (size_t)2048 * 1024, 1024, 1024, 1.f);
  cvt_w_t<<<dim3(16, 16), 256, 0, stream>>>(Wo, Wot, 1024, 1024, 1.f);
  // fused q|k|v|gate projection (256^2 8-wave phase-split MFMA)
  gemm256<2><<<dim3(12, 64), 512, 0, stream>>>(xh, Wqkvgt, bg, qkvg, QKVS);
  gemm_g1<<<Mrows / 16, 256, 0, stream>>>(xh, Wg1, t1);
  gemm_g2<<<(Mrows * 512) / 256, 256, 0, stream>>>(t1, Wg2, lgb);
  // chunked recurrence (MFMA) + fused gnorm/gate epilogue
  gla_chunk_state<<<64 * NCHK, 256, 0, stream>>>(qkvg, lgb, Pst, Dd);
  gla_chain<<<64, 256, 0, stream>>>(Pst, Dd);
  gla_chunk_out<<<64 * NCHK, 256, 0, stream>>>(qkvg, lgb, Pst, gated);
  // output projection (fp32 out)
  gemm256<3><<<dim3(4, 64), 512, 0, stream>>>(gated, Wot, nullptr, d_out, 1024);
}